// Round 1
// baseline (41329.865 us; speedup 1.0000x reference)
//
#include <hip/hip_runtime.h>
#include <float.h>

#define TT 4096
#define BB 4
#define CC 512
#define DD 256
#define KK 2048
#define MM (BB*TT)        // 16384 rows (b,t)
#define NBOOKS 22
#define REFINE_CAP 4096
#define EPS_REFINE 0.25f

// merge (best value, best idx, second-best value) triples; ties -> lower idx (np.argmin semantics)
__device__ __forceinline__ void merge3(float& bv, int& bi, float& sv,
                                       float ov, int oi, float osv) {
  if (ov < bv || (ov == bv && oi < bi)) {
    sv = fminf(bv, osv);
    bv = ov; bi = oi;
  } else {
    sv = fminf(sv, ov);
  }
}

// ---------------- projection: xs = Win_s @ x, xa = Win_a @ x  (per b: [256x512]@[512x4096]) ----------------
// outputs stored row-major [M rows (b*T+t)][D]
__global__ __launch_bounds__(256) void proj_kernel(const float* __restrict__ x,
    const float* __restrict__ Ws, const float* __restrict__ Wa,
    float* __restrict__ xs, float* __restrict__ xa)
{
  __shared__ float xt[16*64];     // [c][t]
  __shared__ float wsl[16*68];    // [c][d] padded stride 68 (16B-aligned rows)
  __shared__ float wal[16*68];
  const int tid = threadIdx.x;
  const int t0 = blockIdx.x*64, d0 = blockIdx.y*64, b = blockIdx.z;
  const int u = tid & 63, cq = tid >> 6;       // staging mapping
  const int tx = tid & 15, ty = tid >> 4;      // compute mapping: tx->d group, ty->t group
  const float* xb = x + (size_t)b*CC*TT;
  float accS[4][4] = {{0}}, accA[4][4] = {{0}};
  for (int c0 = 0; c0 < CC; c0 += 16) {
    __syncthreads();
    #pragma unroll
    for (int i = 0; i < 4; ++i) {
      int cc = cq*4 + i;
      xt[cc*64 + u] = xb[(size_t)(c0+cc)*TT + t0 + u];
    }
    {
      float4 wv = *(const float4*)&Ws[(size_t)(d0+u)*CC + c0 + cq*4];
      wsl[(cq*4+0)*68 + u] = wv.x; wsl[(cq*4+1)*68 + u] = wv.y;
      wsl[(cq*4+2)*68 + u] = wv.z; wsl[(cq*4+3)*68 + u] = wv.w;
      wv = *(const float4*)&Wa[(size_t)(d0+u)*CC + c0 + cq*4];
      wal[(cq*4+0)*68 + u] = wv.x; wal[(cq*4+1)*68 + u] = wv.y;
      wal[(cq*4+2)*68 + u] = wv.z; wal[(cq*4+3)*68 + u] = wv.w;
    }
    __syncthreads();
    #pragma unroll
    for (int cc = 0; cc < 16; ++cc) {
      float4 tq = *(const float4*)&xt[cc*64 + ty*4];
      float4 sq = *(const float4*)&wsl[cc*68 + tx*4];
      float4 aq = *(const float4*)&wal[cc*68 + tx*4];
      float tf[4] = {tq.x,tq.y,tq.z,tq.w};
      float sf[4] = {sq.x,sq.y,sq.z,sq.w};
      float af[4] = {aq.x,aq.y,aq.z,aq.w};
      #pragma unroll
      for (int i = 0; i < 4; ++i)
        #pragma unroll
        for (int j = 0; j < 4; ++j) {
          accS[i][j] = fmaf(tf[i], sf[j], accS[i][j]);
          accA[i][j] = fmaf(tf[i], af[j], accA[i][j]);
        }
    }
  }
  #pragma unroll
  for (int i = 0; i < 4; ++i) {
    size_t r = (size_t)b*TT + t0 + ty*4 + i;
    float4 o;
    o.x = accS[i][0]; o.y = accS[i][1]; o.z = accS[i][2]; o.w = accS[i][3];
    *(float4*)&xs[r*DD + d0 + tx*4] = o;
    o.x = accA[i][0]; o.y = accA[i][1]; o.z = accA[i][2]; o.w = accA[i][3];
    *(float4*)&xa[r*DD + d0 + tx*4] = o;
  }
}

// ---------------- e2[k] = sum_d E[k][d]^2 for all 18*2048 rows ----------------
__global__ __launch_bounds__(256) void e2_kernel(const float* __restrict__ E,
    float* __restrict__ e2, int* __restrict__ rcount)
{
  int gid = blockIdx.x*256 + threadIdx.x;
  int wid = gid >> 6, lane = gid & 63;
  if (wid < 18*KK) {
    float4 v = *(const float4*)&E[(size_t)wid*DD + lane*4];
    float s = v.x*v.x + v.y*v.y + v.z*v.z + v.w*v.w;
    #pragma unroll
    for (int m = 1; m <= 32; m <<= 1) s += __shfl_xor(s, m);
    if (lane == 0) e2[wid] = s;
  }
  if (blockIdx.x == 0 && threadIdx.x == 0) *rcount = 0;
}

// ---------------- nearest-code search: per row argmin_k (e2[k] - 2 * z.e_k) ----------------
// 512 threads, 32 rows/block, K processed in slices of 256 codes.
__global__ __launch_bounds__(512, 4) void search_kernel(
    const float* __restrict__ Z, const float* __restrict__ Eb,
    const float* __restrict__ e2b, int* __restrict__ codes,
    int* __restrict__ rcount, int* __restrict__ rlist)
{
  __shared__ float Zl[DD*32];    // [d][r]  32 KB
  __shared__ float El[32*256];   // [d_local][c] 32 KB
  const int tid = threadIdx.x;
  const int row0 = blockIdx.x * 32;
  // stage Z (all 256 d for 32 rows), transposed
  {
    int r = tid & 31, q = tid >> 5;            // q 0..15
    const float* zr = Z + (size_t)(row0 + r)*DD;
    #pragma unroll
    for (int s = 0; s < 4; ++s) {
      int f4 = q + s*16;                       // 0..63
      float4 v = *(const float4*)(zr + f4*4);
      Zl[(f4*4+0)*32 + r] = v.x;
      Zl[(f4*4+1)*32 + r] = v.y;
      Zl[(f4*4+2)*32 + r] = v.z;
      Zl[(f4*4+3)*32 + r] = v.w;
    }
  }
  const int tx = tid & 63, ty = tid >> 6;      // tx: code group (x4), ty: wave -> 4 rows
  const int tx4 = tx*4, ty4 = ty*4;
  const int cst = tid & 255;                   // staging: code index within slice
  const int dh16 = (tid >> 8) * 16;            // staging: d-half offset
  float runv[4], runs[4]; int runi[4];
  #pragma unroll
  for (int i = 0; i < 4; ++i) { runv[i] = FLT_MAX; runs[i] = FLT_MAX; runi[i] = 0x7fffffff; }

  for (int k0 = 0; k0 < KK; k0 += 256) {
    float acc[4][4] = {{0}};
    const float* eb = Eb + (size_t)(k0 + cst)*DD + dh16;
    float4 p0 = *(const float4*)(eb + 0);
    float4 p1 = *(const float4*)(eb + 4);
    float4 p2 = *(const float4*)(eb + 8);
    float4 p3 = *(const float4*)(eb + 12);
    for (int dc = 0; dc < 8; ++dc) {
      __syncthreads();
      El[(dh16+ 0)*256 + cst] = p0.x; El[(dh16+ 1)*256 + cst] = p0.y;
      El[(dh16+ 2)*256 + cst] = p0.z; El[(dh16+ 3)*256 + cst] = p0.w;
      El[(dh16+ 4)*256 + cst] = p1.x; El[(dh16+ 5)*256 + cst] = p1.y;
      El[(dh16+ 6)*256 + cst] = p1.z; El[(dh16+ 7)*256 + cst] = p1.w;
      El[(dh16+ 8)*256 + cst] = p2.x; El[(dh16+ 9)*256 + cst] = p2.y;
      El[(dh16+10)*256 + cst] = p2.z; El[(dh16+11)*256 + cst] = p2.w;
      El[(dh16+12)*256 + cst] = p3.x; El[(dh16+13)*256 + cst] = p3.y;
      El[(dh16+14)*256 + cst] = p3.z; El[(dh16+15)*256 + cst] = p3.w;
      if (dc < 7) {
        const float* e2p = eb + (dc+1)*32;
        p0 = *(const float4*)(e2p + 0);
        p1 = *(const float4*)(e2p + 4);
        p2 = *(const float4*)(e2p + 8);
        p3 = *(const float4*)(e2p + 12);
      }
      __syncthreads();
      const float* zc = Zl + dc*32*32;
      #pragma unroll
      for (int d = 0; d < 32; ++d) {
        float4 zq = *(const float4*)(zc + d*32 + ty4);
        float4 eq = *(const float4*)(El + d*256 + tx4);
        float zf[4] = {zq.x,zq.y,zq.z,zq.w};
        float ef[4] = {eq.x,eq.y,eq.z,eq.w};
        #pragma unroll
        for (int i = 0; i < 4; ++i)
          #pragma unroll
          for (int j = 0; j < 4; ++j)
            acc[i][j] = fmaf(zf[i], ef[j], acc[i][j]);
      }
    }
    // score + reduce
    float4 e2q = *(const float4*)(e2b + k0 + tx4);
    float e2a[4] = {e2q.x,e2q.y,e2q.z,e2q.w};
    #pragma unroll
    for (int i = 0; i < 4; ++i) {
      float bv = fmaf(-2.f, acc[i][0], e2a[0]); int bi = k0 + tx4; float sv = FLT_MAX;
      #pragma unroll
      for (int j = 1; j < 4; ++j) {
        float v = fmaf(-2.f, acc[i][j], e2a[j]);
        merge3(bv, bi, sv, v, k0 + tx4 + j, FLT_MAX);
      }
      #pragma unroll
      for (int m = 1; m <= 32; m <<= 1) {
        float ov  = __shfl_xor(bv, m);
        int   oi  = __shfl_xor(bi, m);
        float osv = __shfl_xor(sv, m);
        merge3(bv, bi, sv, ov, oi, osv);
      }
      if (tx == 0) merge3(runv[i], runi[i], runs[i], bv, bi, sv);
    }
  }
  if (tx == 0) {
    #pragma unroll
    for (int i = 0; i < 4; ++i) {
      int row = row0 + ty4 + i;
      codes[row] = runi[i];
      if (runs[i] - runv[i] < EPS_REFINE) {
        int pos = atomicAdd(rcount, 1);
        if (pos < REFINE_CAP) rlist[pos] = row;
      }
    }
  }
}

// ---------------- fp64 refinement of near-tie rows ----------------
__global__ __launch_bounds__(256) void refine_kernel(const float* __restrict__ Z,
    const float* __restrict__ Eb, int* __restrict__ codes,
    const int* __restrict__ rlist, const int* __restrict__ rcount)
{
  int cnt = *rcount; if (cnt > REFINE_CAP) cnt = REFINE_CAP;
  __shared__ float zrow[DD];
  __shared__ double wbv[4]; __shared__ int wbi[4];
  for (int li = blockIdx.x; li < cnt; li += gridDim.x) {
    int row = rlist[li];
    __syncthreads();
    if (threadIdx.x < 64) {
      float4 v = *(const float4*)&Z[(size_t)row*DD + threadIdx.x*4];
      *(float4*)&zrow[threadIdx.x*4] = v;
    }
    __syncthreads();
    double bestv = DBL_MAX; int besti = 0x7fffffff;
    for (int k = threadIdx.x; k < KK; k += 256) {
      const float* er = Eb + (size_t)k*DD;
      double s = 0.0;
      for (int d = 0; d < DD; d += 4) {
        float4 e = *(const float4*)(er + d);
        double d0 = (double)zrow[d+0] - (double)e.x; s += d0*d0;
        double d1 = (double)zrow[d+1] - (double)e.y; s += d1*d1;
        double d2 = (double)zrow[d+2] - (double)e.z; s += d2*d2;
        double d3 = (double)zrow[d+3] - (double)e.w; s += d3*d3;
      }
      if (s < bestv || (s == bestv && k < besti)) { bestv = s; besti = k; }
    }
    #pragma unroll
    for (int m = 1; m <= 32; m <<= 1) {
      double ov = __shfl_xor(bestv, m);
      int    oi = __shfl_xor(besti, m);
      if (ov < bestv || (ov == bestv && oi < besti)) { bestv = ov; besti = oi; }
    }
    int wv = threadIdx.x >> 6, ln = threadIdx.x & 63;
    if (ln == 0) { wbv[wv] = bestv; wbi[wv] = besti; }
    __syncthreads();
    if (threadIdx.x == 0) {
      double bv = wbv[0]; int bi = wbi[0];
      for (int w = 1; w < 4; ++w)
        if (wbv[w] < bv || (wbv[w] == bv && wbi[w] < bi)) { bv = wbv[w]; bi = wbi[w]; }
      codes[row] = bi;
    }
    __syncthreads();
  }
}

// ---------------- residual subtract + acoustic accumulate + emit code as float ----------------
__global__ __launch_bounds__(256) void subtract_kernel(float* __restrict__ xa,
    float* __restrict__ aco, const float* __restrict__ Eb,
    const int* __restrict__ codes, float* __restrict__ codes_f,
    int* __restrict__ rcount, int book, int do_sub)
{
  if (blockIdx.x == 0 && threadIdx.x == 0) *rcount = 0;  // reset refine counter for next book
  int gid = blockIdx.x*256 + threadIdx.x;
  int row = gid >> 6, lane = gid & 63;
  if (row >= MM) return;
  int code = codes[row];
  if (lane == 0) {
    int b = row >> 12, t = row & (TT-1);
    codes_f[((size_t)b*NBOOKS + book)*TT + t] = (float)code;
  }
  if (do_sub) {
    size_t zi = (size_t)row*DD + lane*4;
    float4 e = *(const float4*)&Eb[(size_t)code*DD + lane*4];
    float4 v = *(const float4*)&xa[zi];
    v.x -= e.x; v.y -= e.y; v.z -= e.z; v.w -= e.w;
    *(float4*)&xa[zi] = v;
    float4 a = *(const float4*)&aco[zi];
    a.x += e.x; a.y += e.y; a.z += e.z; a.w += e.w;
    *(float4*)&aco[zi] = a;
  }
}

// ---------------- decode: out = Wout_s @ gather(E0, codes0) + Wout_a @ aco ----------------
__global__ __launch_bounds__(256) void final_kernel(
    const float* __restrict__ Wos, const float* __restrict__ Woa,
    const float* __restrict__ E0, const int* __restrict__ codes0,
    const float* __restrict__ aco, float* __restrict__ out)
{
  __shared__ float wsl[16*68], wal[16*68], sml[16*68], acl[16*68];
  const int tid = threadIdx.x;
  const int t0 = blockIdx.x*64, c0 = blockIdx.y*64, b = blockIdx.z;
  const int u = tid & 63, dq = tid >> 6;
  const int tx = tid & 15, ty = tid >> 4;    // tx -> c group, ty -> t group
  int code = codes0[b*TT + t0 + u];
  const float* smr = E0 + (size_t)code*DD;
  const float* acr = aco + (size_t)(b*TT + t0 + u)*DD;
  const float* wsr = Wos + (size_t)(c0+u)*DD;
  const float* war = Woa + (size_t)(c0+u)*DD;
  float accS[4][4] = {{0}}, accA[4][4] = {{0}};
  for (int dc0 = 0; dc0 < DD; dc0 += 16) {
    __syncthreads();
    float4 v;
    v = *(const float4*)(wsr + dc0 + dq*4);
    wsl[(dq*4+0)*68+u]=v.x; wsl[(dq*4+1)*68+u]=v.y; wsl[(dq*4+2)*68+u]=v.z; wsl[(dq*4+3)*68+u]=v.w;
    v = *(const float4*)(war + dc0 + dq*4);
    wal[(dq*4+0)*68+u]=v.x; wal[(dq*4+1)*68+u]=v.y; wal[(dq*4+2)*68+u]=v.z; wal[(dq*4+3)*68+u]=v.w;
    v = *(const float4*)(smr + dc0 + dq*4);
    sml[(dq*4+0)*68+u]=v.x; sml[(dq*4+1)*68+u]=v.y; sml[(dq*4+2)*68+u]=v.z; sml[(dq*4+3)*68+u]=v.w;
    v = *(const float4*)(acr + dc0 + dq*4);
    acl[(dq*4+0)*68+u]=v.x; acl[(dq*4+1)*68+u]=v.y; acl[(dq*4+2)*68+u]=v.z; acl[(dq*4+3)*68+u]=v.w;
    __syncthreads();
    #pragma unroll
    for (int d = 0; d < 16; ++d) {
      float4 cs = *(const float4*)&wsl[d*68 + tx*4];
      float4 ca = *(const float4*)&wal[d*68 + tx*4];
      float4 ts = *(const float4*)&sml[d*68 + ty*4];
      float4 ta = *(const float4*)&acl[d*68 + ty*4];
      float csf[4]={cs.x,cs.y,cs.z,cs.w}, caf[4]={ca.x,ca.y,ca.z,ca.w};
      float tsf[4]={ts.x,ts.y,ts.z,ts.w}, taf[4]={ta.x,ta.y,ta.z,ta.w};
      #pragma unroll
      for (int i = 0; i < 4; ++i)
        #pragma unroll
        for (int j = 0; j < 4; ++j) {
          accS[i][j] = fmaf(csf[i], tsf[j], accS[i][j]);
          accA[i][j] = fmaf(caf[i], taf[j], accA[i][j]);
        }
    }
  }
  size_t ob = (size_t)b*CC*TT;
  #pragma unroll
  for (int i = 0; i < 4; ++i) {
    float4 r;
    r.x = accS[i][0] + accA[i][0];
    r.y = accS[i][1] + accA[i][1];
    r.z = accS[i][2] + accA[i][2];
    r.w = accS[i][3] + accA[i][3];
    *(float4*)&out[ob + (size_t)(c0 + tx*4 + i)*TT + t0 + ty*4] = r;
  }
}

extern "C" void kernel_launch(void* const* d_in, const int* in_sizes, int n_in,
                              void* d_out, int out_size, void* d_ws, size_t ws_size,
                              hipStream_t stream) {
  const float* x    = (const float*)d_in[0];
  const float* Wins = (const float*)d_in[1];
  const float* Wina = (const float*)d_in[2];
  const float* Wos  = (const float*)d_in[3];
  const float* Woa  = (const float*)d_in[4];
  const float* E    = (const float*)d_in[5];
  float* out = (float*)d_out;
  float* codes_f = out + (size_t)BB*CC*TT;

  float* xs  = (float*)d_ws;
  float* xa  = xs + (size_t)MM*DD;
  float* aco = xa + (size_t)MM*DD;
  float* e2  = aco + (size_t)MM*DD;
  int* codes_i = (int*)(e2 + 18*KK);
  int* rlist = codes_i + (size_t)NBOOKS*MM;
  int* rcount = rlist + REFINE_CAP;

  static const int BOOKS[21] = {1,2,3,4,5,6,7,8,9,10,11,12,13,14,15,16,17,17,17,17,17};

  hipMemsetAsync(aco, 0, (size_t)MM*DD*sizeof(float), stream);
  proj_kernel<<<dim3(TT/64, DD/64, BB), 256, 0, stream>>>(x, Wins, Wina, xs, xa);
  e2_kernel<<<(18*KK*64)/256, 256, 0, stream>>>(E, e2, rcount);

  // semantic book (E[0], no residual subtract)
  search_kernel<<<MM/32, 512, 0, stream>>>(xs, E, e2, codes_i, rcount, rlist);
  refine_kernel<<<256, 256, 0, stream>>>(xs, E, codes_i, rlist, rcount);
  subtract_kernel<<<(MM*64)/256, 256, 0, stream>>>(xa, aco, E, codes_i, codes_f, rcount, 0, 0);

  for (int ib = 0; ib < 21; ++ib) {
    int cb = BOOKS[ib];
    const float* Eb  = E  + (size_t)cb*KK*DD;
    const float* e2b = e2 + (size_t)cb*KK;
    int* cbk = codes_i + (size_t)(ib+1)*MM;
    search_kernel<<<MM/32, 512, 0, stream>>>(xa, Eb, e2b, cbk, rcount, rlist);
    refine_kernel<<<256, 256, 0, stream>>>(xa, Eb, cbk, rlist, rcount);
    subtract_kernel<<<(MM*64)/256, 256, 0, stream>>>(xa, aco, Eb, cbk, codes_f, rcount, ib+1, 1);
  }

  final_kernel<<<dim3(TT/64, CC/64, BB), 256, 0, stream>>>(Wos, Woa, E, codes_i, aco, out);
}

// Round 2
// 11967.006 us; speedup vs baseline: 3.4537x; 3.4537x over previous
//
#include <hip/hip_runtime.h>
#include <float.h>

#define TT 4096
#define BB 4
#define CC 512
#define DD 256
#define KK 2048
#define MM (BB*TT)        // 16384 rows (b,t)
#define NBOOKS 22
#define REFINE_CAP 4096
#define EPS_REFINE 0.25f

// merge (best value, best idx, second-best value) triples; ties -> lower idx (np.argmin semantics)
__device__ __forceinline__ void merge3(float& bv, int& bi, float& sv,
                                       float ov, int oi, float osv) {
  if (ov < bv || (ov == bv && oi < bi)) {
    sv = fminf(bv, osv);
    bv = ov; bi = oi;
  } else {
    sv = fminf(sv, ov);
  }
}

// ---------------- projection: xs = Win_s @ x, xa = Win_a @ x  (per b: [256x512]@[512x4096]) ----------------
__global__ __launch_bounds__(256) void proj_kernel(const float* __restrict__ x,
    const float* __restrict__ Ws, const float* __restrict__ Wa,
    float* __restrict__ xs, float* __restrict__ xa)
{
  __shared__ float xt[16*64];     // [c][t]
  __shared__ float wsl[16*68];    // [c][d] padded
  __shared__ float wal[16*68];
  const int tid = threadIdx.x;
  const int t0 = blockIdx.x*64, d0 = blockIdx.y*64, b = blockIdx.z;
  const int u = tid & 63, cq = tid >> 6;
  const int tx = tid & 15, ty = tid >> 4;
  const float* xb = x + (size_t)b*CC*TT;
  float accS[4][4] = {{0}}, accA[4][4] = {{0}};
  for (int c0 = 0; c0 < CC; c0 += 16) {
    __syncthreads();
    #pragma unroll
    for (int i = 0; i < 4; ++i) {
      int cc = cq*4 + i;
      xt[cc*64 + u] = xb[(size_t)(c0+cc)*TT + t0 + u];
    }
    {
      float4 wv = *(const float4*)&Ws[(size_t)(d0+u)*CC + c0 + cq*4];
      wsl[(cq*4+0)*68 + u] = wv.x; wsl[(cq*4+1)*68 + u] = wv.y;
      wsl[(cq*4+2)*68 + u] = wv.z; wsl[(cq*4+3)*68 + u] = wv.w;
      wv = *(const float4*)&Wa[(size_t)(d0+u)*CC + c0 + cq*4];
      wal[(cq*4+0)*68 + u] = wv.x; wal[(cq*4+1)*68 + u] = wv.y;
      wal[(cq*4+2)*68 + u] = wv.z; wal[(cq*4+3)*68 + u] = wv.w;
    }
    __syncthreads();
    #pragma unroll
    for (int cc = 0; cc < 16; ++cc) {
      float4 tq = *(const float4*)&xt[cc*64 + ty*4];
      float4 sq = *(const float4*)&wsl[cc*68 + tx*4];
      float4 aq = *(const float4*)&wal[cc*68 + tx*4];
      float tf[4] = {tq.x,tq.y,tq.z,tq.w};
      float sf[4] = {sq.x,sq.y,sq.z,sq.w};
      float af[4] = {aq.x,aq.y,aq.z,aq.w};
      #pragma unroll
      for (int i = 0; i < 4; ++i)
        #pragma unroll
        for (int j = 0; j < 4; ++j) {
          accS[i][j] = fmaf(tf[i], sf[j], accS[i][j]);
          accA[i][j] = fmaf(tf[i], af[j], accA[i][j]);
        }
    }
  }
  #pragma unroll
  for (int i = 0; i < 4; ++i) {
    size_t r = (size_t)b*TT + t0 + ty*4 + i;
    float4 o;
    o.x = accS[i][0]; o.y = accS[i][1]; o.z = accS[i][2]; o.w = accS[i][3];
    *(float4*)&xs[r*DD + d0 + tx*4] = o;
    o.x = accA[i][0]; o.y = accA[i][1]; o.z = accA[i][2]; o.w = accA[i][3];
    *(float4*)&xa[r*DD + d0 + tx*4] = o;
  }
}

// ---------------- e2[k] = sum_d E[k][d]^2 ----------------
__global__ __launch_bounds__(256) void e2_kernel(const float* __restrict__ E,
    float* __restrict__ e2, int* __restrict__ rcount)
{
  int gid = blockIdx.x*256 + threadIdx.x;
  int wid = gid >> 6, lane = gid & 63;
  if (wid < 18*KK) {
    float4 v = *(const float4*)&E[(size_t)wid*DD + lane*4];
    float s = v.x*v.x + v.y*v.y + v.z*v.z + v.w*v.w;
    #pragma unroll
    for (int m = 1; m <= 32; m <<= 1) s += __shfl_xor(s, m);
    if (lane == 0) e2[wid] = s;
  }
  if (blockIdx.x == 0 && threadIdx.x == 0) *rcount = 0;
}

// ---------------- nearest-code search ----------------
// 256 threads, 32 rows/block. Thread tile: 8 rows x 4 codes.
// wave w (= tid>>6) owns rows [w*8, w*8+8); z-reads are wave-uniform (LDS broadcast).
// Per-lane running argmin over its 4-code columns; one butterfly reduce at the end.
__global__ __launch_bounds__(256) void search_kernel(
    const float* __restrict__ Z, const float* __restrict__ Eb,
    const float* __restrict__ e2b, int* __restrict__ codes,
    int* __restrict__ rcount, int* __restrict__ rlist)
{
  __shared__ float Zl[DD*32];      // [d][r]  32 KB
  __shared__ float El[16*260];     // [d_local][c] padded, 16.6 KB
  const int tid = threadIdx.x;
  const int row0 = blockIdx.x * 32;
  // stage Z (all 256 d for 32 rows), transposed
  {
    int r = tid & 31, q = tid >> 5;            // q 0..7
    const float* zr = Z + (size_t)(row0 + r)*DD;
    #pragma unroll
    for (int s = 0; s < 8; ++s) {
      int f4 = q + s*8;                        // 0..63
      float4 v = *(const float4*)(zr + f4*4);
      Zl[(f4*4+0)*32 + r] = v.x;
      Zl[(f4*4+1)*32 + r] = v.y;
      Zl[(f4*4+2)*32 + r] = v.z;
      Zl[(f4*4+3)*32 + r] = v.w;
    }
  }
  const int tx = tid & 63, ty = tid >> 6;      // tx: code group (x4), ty: wave -> 8 rows
  const int tx4 = tx*4, rbase = ty*8;
  const int cbase = tid >> 2, j4 = (tid & 3)*4;   // staging: 4 codes strided 64, 4 d each

  float bv[8], sv[8]; int bi[8];
  #pragma unroll
  for (int i = 0; i < 8; ++i) { bv[i] = FLT_MAX; sv[i] = FLT_MAX; bi[i] = 0x7fffffff; }

  for (int k0 = 0; k0 < KK; k0 += 256) {
    float acc[8][4] = {{0}};
    float4 p[4];
    #pragma unroll
    for (int s = 0; s < 4; ++s)
      p[s] = *(const float4*)&Eb[(size_t)(k0 + cbase + s*64)*DD + j4];
    for (int dc = 0; dc < 16; ++dc) {
      __syncthreads();
      #pragma unroll
      for (int s = 0; s < 4; ++s) {
        int c = cbase + s*64;
        El[(j4+0)*260 + c] = p[s].x;
        El[(j4+1)*260 + c] = p[s].y;
        El[(j4+2)*260 + c] = p[s].z;
        El[(j4+3)*260 + c] = p[s].w;
      }
      if (dc < 15) {
        #pragma unroll
        for (int s = 0; s < 4; ++s)
          p[s] = *(const float4*)&Eb[(size_t)(k0 + cbase + s*64)*DD + (dc+1)*16 + j4];
      }
      __syncthreads();
      const float* zc = Zl + dc*16*32 + rbase;
      #pragma unroll
      for (int dd = 0; dd < 16; ++dd) {
        float4 z0 = *(const float4*)(zc + dd*32);
        float4 z1 = *(const float4*)(zc + dd*32 + 4);
        float4 eq = *(const float4*)(El + dd*260 + tx4);
        float zf[8] = {z0.x,z0.y,z0.z,z0.w,z1.x,z1.y,z1.z,z1.w};
        float ef[4] = {eq.x,eq.y,eq.z,eq.w};
        #pragma unroll
        for (int i = 0; i < 8; ++i)
          #pragma unroll
          for (int j = 0; j < 4; ++j)
            acc[i][j] = fmaf(zf[i], ef[j], acc[i][j]);
      }
    }
    // fold this slice into per-lane running best
    float4 e2q = *(const float4*)(e2b + k0 + tx4);
    float e2a[4] = {e2q.x,e2q.y,e2q.z,e2q.w};
    #pragma unroll
    for (int i = 0; i < 8; ++i)
      #pragma unroll
      for (int j = 0; j < 4; ++j) {
        float v = fmaf(-2.f, acc[i][j], e2a[j]);
        merge3(bv[i], bi[i], sv[i], v, k0 + tx4 + j, FLT_MAX);
      }
  }
  // final cross-lane butterfly per row
  #pragma unroll
  for (int i = 0; i < 8; ++i) {
    float v = bv[i], s = sv[i]; int ix = bi[i];
    #pragma unroll
    for (int m = 1; m <= 32; m <<= 1) {
      float ov = __shfl_xor(v, m);
      int   oi = __shfl_xor(ix, m);
      float os = __shfl_xor(s, m);
      merge3(v, ix, s, ov, oi, os);
    }
    if (tx == 0) {
      int row = row0 + rbase + i;
      codes[row] = ix;
      if (s - v < EPS_REFINE) {
        int pos = atomicAdd(rcount, 1);
        if (pos < REFINE_CAP) rlist[pos] = row;
      }
    }
  }
}

// ---------------- fp64 refinement of near-tie rows ----------------
__global__ __launch_bounds__(256) void refine_kernel(const float* __restrict__ Z,
    const float* __restrict__ Eb, int* __restrict__ codes,
    const int* __restrict__ rlist, const int* __restrict__ rcount)
{
  int cnt = *rcount; if (cnt > REFINE_CAP) cnt = REFINE_CAP;
  __shared__ float zrow[DD];
  __shared__ double wbv[4]; __shared__ int wbi[4];
  for (int li = blockIdx.x; li < cnt; li += gridDim.x) {
    int row = rlist[li];
    __syncthreads();
    if (threadIdx.x < 64) {
      float4 v = *(const float4*)&Z[(size_t)row*DD + threadIdx.x*4];
      *(float4*)&zrow[threadIdx.x*4] = v;
    }
    __syncthreads();
    double bestv = DBL_MAX; int besti = 0x7fffffff;
    for (int k = threadIdx.x; k < KK; k += 256) {
      const float* er = Eb + (size_t)k*DD;
      double s = 0.0;
      for (int d = 0; d < DD; d += 4) {
        float4 e = *(const float4*)(er + d);
        double d0 = (double)zrow[d+0] - (double)e.x; s += d0*d0;
        double d1 = (double)zrow[d+1] - (double)e.y; s += d1*d1;
        double d2 = (double)zrow[d+2] - (double)e.z; s += d2*d2;
        double d3 = (double)zrow[d+3] - (double)e.w; s += d3*d3;
      }
      if (s < bestv || (s == bestv && k < besti)) { bestv = s; besti = k; }
    }
    #pragma unroll
    for (int m = 1; m <= 32; m <<= 1) {
      double ov = __shfl_xor(bestv, m);
      int    oi = __shfl_xor(besti, m);
      if (ov < bestv || (ov == bestv && oi < besti)) { bestv = ov; besti = oi; }
    }
    int wv = threadIdx.x >> 6, ln = threadIdx.x & 63;
    if (ln == 0) { wbv[wv] = bestv; wbi[wv] = besti; }
    __syncthreads();
    if (threadIdx.x == 0) {
      double bv = wbv[0]; int bi = wbi[0];
      for (int w = 1; w < 4; ++w)
        if (wbv[w] < bv || (wbv[w] == bv && wbi[w] < bi)) { bv = wbv[w]; bi = wbi[w]; }
      codes[row] = bi;
    }
    __syncthreads();
  }
}

// ---------------- residual subtract + acoustic accumulate + emit code as float ----------------
__global__ __launch_bounds__(256) void subtract_kernel(float* __restrict__ xa,
    float* __restrict__ aco, const float* __restrict__ Eb,
    const int* __restrict__ codes, float* __restrict__ codes_f,
    int* __restrict__ rcount, int book, int do_sub)
{
  if (blockIdx.x == 0 && threadIdx.x == 0) *rcount = 0;
  int gid = blockIdx.x*256 + threadIdx.x;
  int row = gid >> 6, lane = gid & 63;
  if (row >= MM) return;
  int code = codes[row];
  if (lane == 0) {
    int b = row >> 12, t = row & (TT-1);
    codes_f[((size_t)b*NBOOKS + book)*TT + t] = (float)code;
  }
  if (do_sub) {
    size_t zi = (size_t)row*DD + lane*4;
    float4 e = *(const float4*)&Eb[(size_t)code*DD + lane*4];
    float4 v = *(const float4*)&xa[zi];
    v.x -= e.x; v.y -= e.y; v.z -= e.z; v.w -= e.w;
    *(float4*)&xa[zi] = v;
    float4 a = *(const float4*)&aco[zi];
    a.x += e.x; a.y += e.y; a.z += e.z; a.w += e.w;
    *(float4*)&aco[zi] = a;
  }
}

// ---------------- decode ----------------
__global__ __launch_bounds__(256) void final_kernel(
    const float* __restrict__ Wos, const float* __restrict__ Woa,
    const float* __restrict__ E0, const int* __restrict__ codes0,
    const float* __restrict__ aco, float* __restrict__ out)
{
  __shared__ float wsl[16*68], wal[16*68], sml[16*68], acl[16*68];
  const int tid = threadIdx.x;
  const int t0 = blockIdx.x*64, c0 = blockIdx.y*64, b = blockIdx.z;
  const int u = tid & 63, dq = tid >> 6;
  const int tx = tid & 15, ty = tid >> 4;
  int code = codes0[b*TT + t0 + u];
  const float* smr = E0 + (size_t)code*DD;
  const float* acr = aco + (size_t)(b*TT + t0 + u)*DD;
  const float* wsr = Wos + (size_t)(c0+u)*DD;
  const float* war = Woa + (size_t)(c0+u)*DD;
  float accS[4][4] = {{0}}, accA[4][4] = {{0}};
  for (int dc0 = 0; dc0 < DD; dc0 += 16) {
    __syncthreads();
    float4 v;
    v = *(const float4*)(wsr + dc0 + dq*4);
    wsl[(dq*4+0)*68+u]=v.x; wsl[(dq*4+1)*68+u]=v.y; wsl[(dq*4+2)*68+u]=v.z; wsl[(dq*4+3)*68+u]=v.w;
    v = *(const float4*)(war + dc0 + dq*4);
    wal[(dq*4+0)*68+u]=v.x; wal[(dq*4+1)*68+u]=v.y; wal[(dq*4+2)*68+u]=v.z; wal[(dq*4+3)*68+u]=v.w;
    v = *(const float4*)(smr + dc0 + dq*4);
    sml[(dq*4+0)*68+u]=v.x; sml[(dq*4+1)*68+u]=v.y; sml[(dq*4+2)*68+u]=v.z; sml[(dq*4+3)*68+u]=v.w;
    v = *(const float4*)(acr + dc0 + dq*4);
    acl[(dq*4+0)*68+u]=v.x; acl[(dq*4+1)*68+u]=v.y; acl[(dq*4+2)*68+u]=v.z; acl[(dq*4+3)*68+u]=v.w;
    __syncthreads();
    #pragma unroll
    for (int d = 0; d < 16; ++d) {
      float4 cs = *(const float4*)&wsl[d*68 + tx*4];
      float4 ca = *(const float4*)&wal[d*68 + tx*4];
      float4 ts = *(const float4*)&sml[d*68 + ty*4];
      float4 ta = *(const float4*)&acl[d*68 + ty*4];
      float csf[4]={cs.x,cs.y,cs.z,cs.w}, caf[4]={ca.x,ca.y,ca.z,ca.w};
      float tsf[4]={ts.x,ts.y,ts.z,ts.w}, taf[4]={ta.x,ta.y,ta.z,ta.w};
      #pragma unroll
      for (int i = 0; i < 4; ++i)
        #pragma unroll
        for (int j = 0; j < 4; ++j) {
          accS[i][j] = fmaf(csf[i], tsf[j], accS[i][j]);
          accA[i][j] = fmaf(caf[i], taf[j], accA[i][j]);
        }
    }
  }
  size_t ob = (size_t)b*CC*TT;
  #pragma unroll
  for (int i = 0; i < 4; ++i) {
    float4 r;
    r.x = accS[i][0] + accA[i][0];
    r.y = accS[i][1] + accA[i][1];
    r.z = accS[i][2] + accA[i][2];
    r.w = accS[i][3] + accA[i][3];
    *(float4*)&out[ob + (size_t)(c0 + tx*4 + i)*TT + t0 + ty*4] = r;
  }
}

extern "C" void kernel_launch(void* const* d_in, const int* in_sizes, int n_in,
                              void* d_out, int out_size, void* d_ws, size_t ws_size,
                              hipStream_t stream) {
  const float* x    = (const float*)d_in[0];
  const float* Wins = (const float*)d_in[1];
  const float* Wina = (const float*)d_in[2];
  const float* Wos  = (const float*)d_in[3];
  const float* Woa  = (const float*)d_in[4];
  const float* E    = (const float*)d_in[5];
  float* out = (float*)d_out;
  float* codes_f = out + (size_t)BB*CC*TT;

  float* xs  = (float*)d_ws;
  float* xa  = xs + (size_t)MM*DD;
  float* aco = xa + (size_t)MM*DD;
  float* e2  = aco + (size_t)MM*DD;
  int* codes_i = (int*)(e2 + 18*KK);
  int* rlist = codes_i + (size_t)NBOOKS*MM;
  int* rcount = rlist + REFINE_CAP;

  static const int BOOKS[21] = {1,2,3,4,5,6,7,8,9,10,11,12,13,14,15,16,17,17,17,17,17};

  hipMemsetAsync(aco, 0, (size_t)MM*DD*sizeof(float), stream);
  proj_kernel<<<dim3(TT/64, DD/64, BB), 256, 0, stream>>>(x, Wins, Wina, xs, xa);
  e2_kernel<<<(18*KK*64)/256, 256, 0, stream>>>(E, e2, rcount);

  // semantic book (E[0], no residual subtract)
  search_kernel<<<MM/32, 256, 0, stream>>>(xs, E, e2, codes_i, rcount, rlist);
  refine_kernel<<<256, 256, 0, stream>>>(xs, E, codes_i, rlist, rcount);
  subtract_kernel<<<(MM*64)/256, 256, 0, stream>>>(xa, aco, E, codes_i, codes_f, rcount, 0, 0);

  for (int ib = 0; ib < 21; ++ib) {
    int cb = BOOKS[ib];
    const float* Eb  = E  + (size_t)cb*KK*DD;
    const float* e2b = e2 + (size_t)cb*KK;
    int* cbk = codes_i + (size_t)(ib+1)*MM;
    search_kernel<<<MM/32, 256, 0, stream>>>(xa, Eb, e2b, cbk, rcount, rlist);
    refine_kernel<<<256, 256, 0, stream>>>(xa, Eb, cbk, rlist, rcount);
    subtract_kernel<<<(MM*64)/256, 256, 0, stream>>>(xa, aco, Eb, cbk, codes_f, rcount, ib+1, 1);
  }

  final_kernel<<<dim3(TT/64, CC/64, BB), 256, 0, stream>>>(Wos, Woa, E, codes_i, aco, out);
}

// Round 4
// 5221.963 us; speedup vs baseline: 7.9146x; 2.2917x over previous
//
#include <hip/hip_runtime.h>
#include <float.h>

#define TT 4096
#define BB 4
#define CC 512
#define DD 256
#define KK 2048
#define MM (BB*TT)        // 16384 rows (b,t)
#define NBOOKS 22
#define REFINE_CAP 16384
#define EPS_REFINE 0.25f

typedef _Float16 half8_t __attribute__((ext_vector_type(8)));
typedef float f32x4 __attribute__((ext_vector_type(4)));

// merge (best value, best idx, second-best value) triples; ties -> lower idx (np.argmin semantics)
__device__ __forceinline__ void merge3(float& bv, int& bi, float& sv,
                                       float ov, int oi, float osv) {
  if (ov < bv || (ov == bv && oi < bi)) {
    sv = fminf(bv, osv);
    bv = ov; bi = oi;
  } else {
    sv = fminf(sv, ov);
  }
}

// ---------------- projection: xs = Win_s @ x, xa = Win_a @ x  (per b: [256x512]@[512x4096]) ----------------
__global__ __launch_bounds__(256) void proj_kernel(const float* __restrict__ x,
    const float* __restrict__ Ws, const float* __restrict__ Wa,
    float* __restrict__ xs, float* __restrict__ xa)
{
  __shared__ float xt[16*64];     // [c][t]
  __shared__ float wsl[16*68];    // [c][d] padded
  __shared__ float wal[16*68];
  const int tid = threadIdx.x;
  const int t0 = blockIdx.x*64, d0 = blockIdx.y*64, b = blockIdx.z;
  const int u = tid & 63, cq = tid >> 6;
  const int tx = tid & 15, ty = tid >> 4;
  const float* xb = x + (size_t)b*CC*TT;
  float accS[4][4] = {{0}}, accA[4][4] = {{0}};
  for (int c0 = 0; c0 < CC; c0 += 16) {
    __syncthreads();
    #pragma unroll
    for (int i = 0; i < 4; ++i) {
      int cc = cq*4 + i;
      xt[cc*64 + u] = xb[(size_t)(c0+cc)*TT + t0 + u];
    }
    {
      float4 wv = *(const float4*)&Ws[(size_t)(d0+u)*CC + c0 + cq*4];
      wsl[(cq*4+0)*68 + u] = wv.x; wsl[(cq*4+1)*68 + u] = wv.y;
      wsl[(cq*4+2)*68 + u] = wv.z; wsl[(cq*4+3)*68 + u] = wv.w;
      wv = *(const float4*)&Wa[(size_t)(d0+u)*CC + c0 + cq*4];
      wal[(cq*4+0)*68 + u] = wv.x; wal[(cq*4+1)*68 + u] = wv.y;
      wal[(cq*4+2)*68 + u] = wv.z; wal[(cq*4+3)*68 + u] = wv.w;
    }
    __syncthreads();
    #pragma unroll
    for (int cc = 0; cc < 16; ++cc) {
      float4 tq = *(const float4*)&xt[cc*64 + ty*4];
      float4 sq = *(const float4*)&wsl[cc*68 + tx*4];
      float4 aq = *(const float4*)&wal[cc*68 + tx*4];
      float tf[4] = {tq.x,tq.y,tq.z,tq.w};
      float sf[4] = {sq.x,sq.y,sq.z,sq.w};
      float af[4] = {aq.x,aq.y,aq.z,aq.w};
      #pragma unroll
      for (int i = 0; i < 4; ++i)
        #pragma unroll
        for (int j = 0; j < 4; ++j) {
          accS[i][j] = fmaf(tf[i], sf[j], accS[i][j]);
          accA[i][j] = fmaf(tf[i], af[j], accA[i][j]);
        }
    }
  }
  #pragma unroll
  for (int i = 0; i < 4; ++i) {
    size_t r = (size_t)b*TT + t0 + ty*4 + i;
    float4 o;
    o.x = accS[i][0]; o.y = accS[i][1]; o.z = accS[i][2]; o.w = accS[i][3];
    *(float4*)&xs[r*DD + d0 + tx*4] = o;
    o.x = accA[i][0]; o.y = accA[i][1]; o.z = accA[i][2]; o.w = accA[i][3];
    *(float4*)&xa[r*DD + d0 + tx*4] = o;
  }
}

// ---------------- e2[k] = sum_d E[k][d]^2 ----------------
__global__ __launch_bounds__(256) void e2_kernel(const float* __restrict__ E,
    float* __restrict__ e2, int* __restrict__ rcount)
{
  int gid = blockIdx.x*256 + threadIdx.x;
  int wid = gid >> 6, lane = gid & 63;
  if (wid < 18*KK) {
    float4 v = *(const float4*)&E[(size_t)wid*DD + lane*4];
    float s = v.x*v.x + v.y*v.y + v.z*v.z + v.w*v.w;
    #pragma unroll
    for (int m = 1; m <= 32; m <<= 1) s += __shfl_xor(s, m);
    if (lane == 0) e2[wid] = s;
  }
  if (blockIdx.x == 0 && threadIdx.x == 0) *rcount = 0;
}

// ---------------- convert E -> f16 plane (stored in front of d_out, dead by final_kernel) ----------------
__global__ __launch_bounds__(256) void cvt_e16_kernel(const float* __restrict__ E,
    _Float16* __restrict__ E16)
{
  size_t i = ((size_t)blockIdx.x*256 + threadIdx.x)*8;
  float4 u = *(const float4*)&E[i];
  float4 v = *(const float4*)&E[i+4];
  half8_t h;
  h[0]=(_Float16)u.x; h[1]=(_Float16)u.y; h[2]=(_Float16)u.z; h[3]=(_Float16)u.w;
  h[4]=(_Float16)v.x; h[5]=(_Float16)v.y; h[6]=(_Float16)v.z; h[7]=(_Float16)v.w;
  *(half8_t*)&E16[i] = h;
}

// ---------------- nearest-code search via f16 MFMA (race-free) ----------------
// 512 blocks x 32 rows. 512 threads = 8 waves = (code-quarter h 0..3) x (row-half p 0..1).
// Each wave: 16 rows x 512 codes, A held in registers, B streamed from E16 (L2).
// Partial (best, idx, second) per code-quarter merged across waves via LDS.
__global__ __launch_bounds__(512) void search_kernel(
    const float* __restrict__ Z, const _Float16* __restrict__ E16b,
    const float* __restrict__ e2b, int* __restrict__ codes,
    int* __restrict__ rcount, int* __restrict__ rlist)
{
  const int tid = threadIdx.x;
  const int lane = tid & 63, wave = tid >> 6;
  const int h = wave & 3, p = wave >> 2;       // code quarter, row half
  const int ln15 = lane & 15, lq = lane >> 4;  // lq 0..3
  const int row0 = blockIdx.x * 32;

  // A fragments: 16 rows x 256 k, f32 -> f16, held for the whole book
  half8_t A[8];
  {
    const float* zr = Z + (size_t)(row0 + p*16 + ln15)*DD + lq*8;
    #pragma unroll
    for (int ks = 0; ks < 8; ++ks) {
      float4 u = *(const float4*)(zr + ks*32);
      float4 v = *(const float4*)(zr + ks*32 + 4);
      half8_t a;
      a[0]=(_Float16)u.x; a[1]=(_Float16)u.y; a[2]=(_Float16)u.z; a[3]=(_Float16)u.w;
      a[4]=(_Float16)v.x; a[5]=(_Float16)v.y; a[6]=(_Float16)v.z; a[7]=(_Float16)v.w;
      A[ks] = a;
    }
  }

  float bv[4], sv[4]; int bi[4];
  #pragma unroll
  for (int j = 0; j < 4; ++j) { bv[j] = FLT_MAX; sv[j] = FLT_MAX; bi[j] = 0x7fffffff; }

  const _Float16* bbase = E16b + (size_t)(h*512 + ln15)*DD + lq*8;

  for (int tg = 0; tg < 32; tg += 4) {         // 4 n-tiles per group
    f32x4 acc[4];
    #pragma unroll
    for (int nt = 0; nt < 4; ++nt) acc[nt] = (f32x4){0.f,0.f,0.f,0.f};
    const _Float16* bp = bbase + (size_t)tg*16*DD;
    half8_t b[4], nb[4];
    #pragma unroll
    for (int nt = 0; nt < 4; ++nt) b[nt] = *(const half8_t*)(bp + nt*16*DD);
    #pragma unroll
    for (int ks = 0; ks < 8; ++ks) {
      if (ks < 7) {
        #pragma unroll
        for (int nt = 0; nt < 4; ++nt)
          nb[nt] = *(const half8_t*)(bp + nt*16*DD + (ks+1)*32);
      }
      #pragma unroll
      for (int nt = 0; nt < 4; ++nt)
        acc[nt] = __builtin_amdgcn_mfma_f32_16x16x32_f16(A[ks], b[nt], acc[nt], 0, 0, 0);
      if (ks < 7) {
        #pragma unroll
        for (int nt = 0; nt < 4; ++nt) b[nt] = nb[nt];
      }
    }
    // scores + running per-lane argmin. C/D: col(code)=lane&15, row=(lane>>4)*4+reg
    #pragma unroll
    for (int nt = 0; nt < 4; ++nt) {
      int code = (h*32 + tg + nt)*16 + ln15;
      float e2v = e2b[code];
      #pragma unroll
      for (int j = 0; j < 4; ++j) {
        float v = fmaf(-2.f, acc[nt][j], e2v);
        merge3(bv[j], bi[j], sv[j], v, code, FLT_MAX);
      }
    }
  }

  // in-wave reduce across the 16 code-columns (ln15 bits)
  __shared__ float Lv[4][32], Ls[4][32];
  __shared__ int   Li[4][32];
  #pragma unroll
  for (int j = 0; j < 4; ++j) {
    float v = bv[j], s = sv[j]; int ix = bi[j];
    #pragma unroll
    for (int m = 1; m <= 8; m <<= 1) {
      float ov = __shfl_xor(v, m);
      int   oi = __shfl_xor(ix, m);
      float os = __shfl_xor(s, m);
      merge3(v, ix, s, ov, oi, os);
    }
    if (ln15 == 0) {
      int rl = p*16 + lq*4 + j;
      Lv[h][rl] = v; Li[h][rl] = ix; Ls[h][rl] = s;
    }
  }
  __syncthreads();
  // merge the 4 code-quarters; single writer per row
  if (tid < 32) {
    float v = Lv[0][tid], s = Ls[0][tid]; int ix = Li[0][tid];
    #pragma unroll
    for (int hh = 1; hh < 4; ++hh)
      merge3(v, ix, s, Lv[hh][tid], Li[hh][tid], Ls[hh][tid]);
    int row = row0 + tid;
    codes[row] = ix;
    if (s - v < EPS_REFINE) {
      int pos = atomicAdd(rcount, 1);
      if (pos < REFINE_CAP) rlist[pos] = row;
    }
  }
}

// ---------------- fp64 refinement of near-tie rows ----------------
__global__ __launch_bounds__(256) void refine_kernel(const float* __restrict__ Z,
    const float* __restrict__ Eb, int* __restrict__ codes,
    const int* __restrict__ rlist, const int* __restrict__ rcount)
{
  int cnt = *rcount; if (cnt > REFINE_CAP) cnt = REFINE_CAP;
  __shared__ float zrow[DD];
  __shared__ double wbv[4]; __shared__ int wbi[4];
  for (int li = blockIdx.x; li < cnt; li += gridDim.x) {
    int row = rlist[li];
    __syncthreads();
    if (threadIdx.x < 64) {
      float4 v = *(const float4*)&Z[(size_t)row*DD + threadIdx.x*4];
      *(float4*)&zrow[threadIdx.x*4] = v;
    }
    __syncthreads();
    double bestv = DBL_MAX; int besti = 0x7fffffff;
    for (int k = threadIdx.x; k < KK; k += 256) {
      const float* er = Eb + (size_t)k*DD;
      double s = 0.0;
      for (int d = 0; d < DD; d += 4) {
        float4 e = *(const float4*)(er + d);
        double d0 = (double)zrow[d+0] - (double)e.x; s += d0*d0;
        double d1 = (double)zrow[d+1] - (double)e.y; s += d1*d1;
        double d2 = (double)zrow[d+2] - (double)e.z; s += d2*d2;
        double d3 = (double)zrow[d+3] - (double)e.w; s += d3*d3;
      }
      if (s < bestv || (s == bestv && k < besti)) { bestv = s; besti = k; }
    }
    #pragma unroll
    for (int m = 1; m <= 32; m <<= 1) {
      double ov = __shfl_xor(bestv, m);
      int    oi = __shfl_xor(besti, m);
      if (ov < bestv || (ov == bestv && oi < besti)) { bestv = ov; besti = oi; }
    }
    int wv = threadIdx.x >> 6, ln = threadIdx.x & 63;
    if (ln == 0) { wbv[wv] = bestv; wbi[wv] = besti; }
    __syncthreads();
    if (threadIdx.x == 0) {
      double bvv = wbv[0]; int bii = wbi[0];
      for (int w = 1; w < 4; ++w)
        if (wbv[w] < bvv || (wbv[w] == bvv && wbi[w] < bii)) { bvv = wbv[w]; bii = wbi[w]; }
      codes[row] = bii;
    }
    __syncthreads();
  }
}

// ---------------- residual subtract + acoustic accumulate + emit code as float ----------------
__global__ __launch_bounds__(256) void subtract_kernel(float* __restrict__ xa,
    float* __restrict__ aco, const float* __restrict__ Eb,
    const int* __restrict__ codes, float* __restrict__ codes_f,
    int* __restrict__ rcount, int book, int do_sub)
{
  if (blockIdx.x == 0 && threadIdx.x == 0) *rcount = 0;
  int gid = blockIdx.x*256 + threadIdx.x;
  int row = gid >> 6, lane = gid & 63;
  if (row >= MM) return;
  int code = codes[row];
  if (lane == 0) {
    int b = row >> 12, t = row & (TT-1);
    codes_f[((size_t)b*NBOOKS + book)*TT + t] = (float)code;
  }
  if (do_sub) {
    size_t zi = (size_t)row*DD + lane*4;
    float4 e = *(const float4*)&Eb[(size_t)code*DD + lane*4];
    float4 v = *(const float4*)&xa[zi];
    v.x -= e.x; v.y -= e.y; v.z -= e.z; v.w -= e.w;
    *(float4*)&xa[zi] = v;
    float4 a = *(const float4*)&aco[zi];
    a.x += e.x; a.y += e.y; a.z += e.z; a.w += e.w;
    *(float4*)&aco[zi] = a;
  }
}

// ---------------- decode ----------------
__global__ __launch_bounds__(256) void final_kernel(
    const float* __restrict__ Wos, const float* __restrict__ Woa,
    const float* __restrict__ E0, const int* __restrict__ codes0,
    const float* __restrict__ aco, float* __restrict__ out)
{
  __shared__ float wsl[16*68], wal[16*68], sml[16*68], acl[16*68];
  const int tid = threadIdx.x;
  const int t0 = blockIdx.x*64, c0 = blockIdx.y*64, b = blockIdx.z;
  const int u = tid & 63, dq = tid >> 6;
  const int tx = tid & 15, ty = tid >> 4;
  int code = codes0[b*TT + t0 + u];
  const float* smr = E0 + (size_t)code*DD;
  const float* acr = aco + (size_t)(b*TT + t0 + u)*DD;
  const float* wsr = Wos + (size_t)(c0+u)*DD;
  const float* war = Woa + (size_t)(c0+u)*DD;
  float accS[4][4] = {{0}}, accA[4][4] = {{0}};
  for (int dc0 = 0; dc0 < DD; dc0 += 16) {
    __syncthreads();
    float4 v;
    v = *(const float4*)(wsr + dc0 + dq*4);
    wsl[(dq*4+0)*68+u]=v.x; wsl[(dq*4+1)*68+u]=v.y; wsl[(dq*4+2)*68+u]=v.z; wsl[(dq*4+3)*68+u]=v.w;
    v = *(const float4*)(war + dc0 + dq*4);
    wal[(dq*4+0)*68+u]=v.x; wal[(dq*4+1)*68+u]=v.y; wal[(dq*4+2)*68+u]=v.z; wal[(dq*4+3)*68+u]=v.w;
    v = *(const float4*)(smr + dc0 + dq*4);
    sml[(dq*4+0)*68+u]=v.x; sml[(dq*4+1)*68+u]=v.y; sml[(dq*4+2)*68+u]=v.z; sml[(dq*4+3)*68+u]=v.w;
    v = *(const float4*)(acr + dc0 + dq*4);
    acl[(dq*4+0)*68+u]=v.x; acl[(dq*4+1)*68+u]=v.y; acl[(dq*4+2)*68+u]=v.z; acl[(dq*4+3)*68+u]=v.w;
    __syncthreads();
    #pragma unroll
    for (int d = 0; d < 16; ++d) {
      float4 cs = *(const float4*)&wsl[d*68 + tx*4];
      float4 ca = *(const float4*)&wal[d*68 + tx*4];
      float4 ts = *(const float4*)&sml[d*68 + ty*4];
      float4 ta = *(const float4*)&acl[d*68 + ty*4];
      float csf[4]={cs.x,cs.y,cs.z,cs.w}, caf[4]={ca.x,ca.y,ca.z,ca.w};
      float tsf[4]={ts.x,ts.y,ts.z,ts.w}, taf[4]={ta.x,ta.y,ta.z,ta.w};
      #pragma unroll
      for (int i = 0; i < 4; ++i)
        #pragma unroll
        for (int j = 0; j < 4; ++j) {
          accS[i][j] = fmaf(csf[i], tsf[j], accS[i][j]);
          accA[i][j] = fmaf(caf[i], taf[j], accA[i][j]);
        }
    }
  }
  size_t ob = (size_t)b*CC*TT;
  #pragma unroll
  for (int i = 0; i < 4; ++i) {
    float4 r;
    r.x = accS[i][0] + accA[i][0];
    r.y = accS[i][1] + accA[i][1];
    r.z = accS[i][2] + accA[i][2];
    r.w = accS[i][3] + accA[i][3];
    *(float4*)&out[ob + (size_t)(c0 + tx*4 + i)*TT + t0 + ty*4] = r;
  }
}

extern "C" void kernel_launch(void* const* d_in, const int* in_sizes, int n_in,
                              void* d_out, int out_size, void* d_ws, size_t ws_size,
                              hipStream_t stream) {
  const float* x    = (const float*)d_in[0];
  const float* Wins = (const float*)d_in[1];
  const float* Wina = (const float*)d_in[2];
  const float* Wos  = (const float*)d_in[3];
  const float* Woa  = (const float*)d_in[4];
  const float* E    = (const float*)d_in[5];
  float* out = (float*)d_out;
  float* codes_f = out + (size_t)BB*CC*TT;

  // E16 plane lives in the front of d_out (18.9MB; codes_f starts at 33.6MB;
  // out[0:8.4M floats] fully overwritten by final_kernel afterwards).
  _Float16* E16 = (_Float16*)d_out;

  float* xs  = (float*)d_ws;
  float* xa  = xs + (size_t)MM*DD;
  float* aco = xa + (size_t)MM*DD;
  float* e2  = aco + (size_t)MM*DD;
  int* codes_i = (int*)(e2 + 18*KK);
  int* rlist = codes_i + (size_t)NBOOKS*MM;
  int* rcount = rlist + REFINE_CAP;

  static const int BOOKS[21] = {1,2,3,4,5,6,7,8,9,10,11,12,13,14,15,16,17,17,17,17,17};

  hipMemsetAsync(aco, 0, (size_t)MM*DD*sizeof(float), stream);
  proj_kernel<<<dim3(TT/64, DD/64, BB), 256, 0, stream>>>(x, Wins, Wina, xs, xa);
  e2_kernel<<<(18*KK*64)/256, 256, 0, stream>>>(E, e2, rcount);
  cvt_e16_kernel<<<(18*KK*DD)/8/256, 256, 0, stream>>>(E, E16);

  // semantic book (E[0], no residual subtract)
  search_kernel<<<MM/32, 512, 0, stream>>>(xs, E16, e2, codes_i, rcount, rlist);
  refine_kernel<<<256, 256, 0, stream>>>(xs, E, codes_i, rlist, rcount);
  subtract_kernel<<<(MM*64)/256, 256, 0, stream>>>(xa, aco, E, codes_i, codes_f, rcount, 0, 0);

  for (int ib = 0; ib < 21; ++ib) {
    int cb = BOOKS[ib];
    const float* Eb  = E  + (size_t)cb*KK*DD;
    const _Float16* E16b = E16 + (size_t)cb*KK*DD;
    const float* e2b = e2 + (size_t)cb*KK;
    int* cbk = codes_i + (size_t)(ib+1)*MM;
    search_kernel<<<MM/32, 512, 0, stream>>>(xa, E16b, e2b, cbk, rcount, rlist);
    refine_kernel<<<256, 256, 0, stream>>>(xa, Eb, cbk, rlist, rcount);
    subtract_kernel<<<(MM*64)/256, 256, 0, stream>>>(xa, aco, Eb, cbk, codes_f, rcount, ib+1, 1);
  }

  final_kernel<<<dim3(TT/64, CC/64, BB), 256, 0, stream>>>(Wos, Woa, E, codes_i, aco, out);
}

// Round 5
// 3773.902 us; speedup vs baseline: 10.9515x; 1.3837x over previous
//
#include <hip/hip_runtime.h>
#include <float.h>

#define TT 4096
#define BB 4
#define CC 512
#define DD 256
#define KK 2048
#define MM (BB*TT)        // 16384 rows (b,t)
#define NBOOKS 22
#define REFINE_CAP 16384
#define EPS_REFINE 0.25f

typedef _Float16 half8_t __attribute__((ext_vector_type(8)));
typedef float f32x4 __attribute__((ext_vector_type(4)));

// merge (best value, best idx, second-best value) triples; ties -> lower idx (np.argmin semantics)
__device__ __forceinline__ void merge3(float& bv, int& bi, float& sv,
                                       float ov, int oi, float osv) {
  if (ov < bv || (ov == bv && oi < bi)) {
    sv = fminf(bv, osv);
    bv = ov; bi = oi;
  } else {
    sv = fminf(sv, ov);
  }
}

// ---------------- projection: xs = Win_s @ x, xa = Win_a @ x  (per b: [256x512]@[512x4096]) ----------------
__global__ __launch_bounds__(256) void proj_kernel(const float* __restrict__ x,
    const float* __restrict__ Ws, const float* __restrict__ Wa,
    float* __restrict__ xs, float* __restrict__ xa)
{
  __shared__ float xt[16*64];     // [c][t]
  __shared__ float wsl[16*68];    // [c][d] padded
  __shared__ float wal[16*68];
  const int tid = threadIdx.x;
  const int t0 = blockIdx.x*64, d0 = blockIdx.y*64, b = blockIdx.z;
  const int u = tid & 63, cq = tid >> 6;
  const int tx = tid & 15, ty = tid >> 4;
  const float* xb = x + (size_t)b*CC*TT;
  float accS[4][4] = {{0}}, accA[4][4] = {{0}};
  for (int c0 = 0; c0 < CC; c0 += 16) {
    __syncthreads();
    #pragma unroll
    for (int i = 0; i < 4; ++i) {
      int cc = cq*4 + i;
      xt[cc*64 + u] = xb[(size_t)(c0+cc)*TT + t0 + u];
    }
    {
      float4 wv = *(const float4*)&Ws[(size_t)(d0+u)*CC + c0 + cq*4];
      wsl[(cq*4+0)*68 + u] = wv.x; wsl[(cq*4+1)*68 + u] = wv.y;
      wsl[(cq*4+2)*68 + u] = wv.z; wsl[(cq*4+3)*68 + u] = wv.w;
      wv = *(const float4*)&Wa[(size_t)(d0+u)*CC + c0 + cq*4];
      wal[(cq*4+0)*68 + u] = wv.x; wal[(cq*4+1)*68 + u] = wv.y;
      wal[(cq*4+2)*68 + u] = wv.z; wal[(cq*4+3)*68 + u] = wv.w;
    }
    __syncthreads();
    #pragma unroll
    for (int cc = 0; cc < 16; ++cc) {
      float4 tq = *(const float4*)&xt[cc*64 + ty*4];
      float4 sq = *(const float4*)&wsl[cc*68 + tx*4];
      float4 aq = *(const float4*)&wal[cc*68 + tx*4];
      float tf[4] = {tq.x,tq.y,tq.z,tq.w};
      float sf[4] = {sq.x,sq.y,sq.z,sq.w};
      float af[4] = {aq.x,aq.y,aq.z,aq.w};
      #pragma unroll
      for (int i = 0; i < 4; ++i)
        #pragma unroll
        for (int j = 0; j < 4; ++j) {
          accS[i][j] = fmaf(tf[i], sf[j], accS[i][j]);
          accA[i][j] = fmaf(tf[i], af[j], accA[i][j]);
        }
    }
  }
  #pragma unroll
  for (int i = 0; i < 4; ++i) {
    size_t r = (size_t)b*TT + t0 + ty*4 + i;
    float4 o;
    o.x = accS[i][0]; o.y = accS[i][1]; o.z = accS[i][2]; o.w = accS[i][3];
    *(float4*)&xs[r*DD + d0 + tx*4] = o;
    o.x = accA[i][0]; o.y = accA[i][1]; o.z = accA[i][2]; o.w = accA[i][3];
    *(float4*)&xa[r*DD + d0 + tx*4] = o;
  }
}

// ---------------- e2[k] = sum_d E[k][d]^2 ----------------
__global__ __launch_bounds__(256) void e2_kernel(const float* __restrict__ E,
    float* __restrict__ e2, int* __restrict__ rcount)
{
  int gid = blockIdx.x*256 + threadIdx.x;
  int wid = gid >> 6, lane = gid & 63;
  if (wid < 18*KK) {
    float4 v = *(const float4*)&E[(size_t)wid*DD + lane*4];
    float s = v.x*v.x + v.y*v.y + v.z*v.z + v.w*v.w;
    #pragma unroll
    for (int m = 1; m <= 32; m <<= 1) s += __shfl_xor(s, m);
    if (lane == 0) e2[wid] = s;
  }
  if (blockIdx.x == 0 && threadIdx.x == 0) *rcount = 0;
}

// ---------------- convert E -> f16 plane (stored in front of d_out, dead by final_kernel) ----------------
__global__ __launch_bounds__(256) void cvt_e16_kernel(const float* __restrict__ E,
    _Float16* __restrict__ E16)
{
  size_t i = ((size_t)blockIdx.x*256 + threadIdx.x)*8;
  float4 u = *(const float4*)&E[i];
  float4 v = *(const float4*)&E[i+4];
  half8_t h;
  h[0]=(_Float16)u.x; h[1]=(_Float16)u.y; h[2]=(_Float16)u.z; h[3]=(_Float16)u.w;
  h[4]=(_Float16)v.x; h[5]=(_Float16)v.y; h[6]=(_Float16)v.z; h[7]=(_Float16)v.w;
  *(half8_t*)&E16[i] = h;
}

// ---------------- nearest-code search via f16 MFMA ----------------
// 256 blocks x 64 rows. 512 threads = 8 waves; ALL waves hold the same 64 rows
// of A (4 M-tiles, f32->f16, in registers); wave w owns codes [w*256, w*256+256)
// (16 n-tiles), so the E16 book is read exactly ONCE per block from L2.
// Per n-tile: 8 prefetched B loads -> 32 MFMAs (4 M-reuse). Cross-wave merge via LDS.
__global__ __launch_bounds__(512) void search_kernel(
    const float* __restrict__ Z, const _Float16* __restrict__ E16b,
    const float* __restrict__ e2b, int* __restrict__ codes,
    int* __restrict__ rcount, int* __restrict__ rlist)
{
  const int tid = threadIdx.x;
  const int lane = tid & 63, wave = tid >> 6;
  const int ln15 = lane & 15, lq = lane >> 4;  // lq 0..3
  const int row0 = blockIdx.x * 64;

  // A fragments: 4 M-tiles x 8 k-steps (whole 64-row, 256-k panel), held all book
  half8_t A[4][8];
  #pragma unroll
  for (int mt = 0; mt < 4; ++mt) {
    const float* zr = Z + (size_t)(row0 + mt*16 + ln15)*DD + lq*8;
    #pragma unroll
    for (int ks = 0; ks < 8; ++ks) {
      float4 u = *(const float4*)(zr + ks*32);
      float4 v = *(const float4*)(zr + ks*32 + 4);
      half8_t a;
      a[0]=(_Float16)u.x; a[1]=(_Float16)u.y; a[2]=(_Float16)u.z; a[3]=(_Float16)u.w;
      a[4]=(_Float16)v.x; a[5]=(_Float16)v.y; a[6]=(_Float16)v.z; a[7]=(_Float16)v.w;
      A[mt][ks] = a;
    }
  }

  float bv[4][4], sv[4][4]; int bi[4][4];
  #pragma unroll
  for (int mt = 0; mt < 4; ++mt)
    #pragma unroll
    for (int j = 0; j < 4; ++j) { bv[mt][j] = FLT_MAX; sv[mt][j] = FLT_MAX; bi[mt][j] = 0x7fffffff; }

  const _Float16* ebase = E16b + (size_t)(wave*256 + ln15)*DD + lq*8;

  half8_t B[8], NB[8];
  #pragma unroll
  for (int ks = 0; ks < 8; ++ks) B[ks] = *(const half8_t*)(ebase + ks*32);

  for (int nt = 0; nt < 16; ++nt) {
    if (nt < 15) {
      const _Float16* np_ = ebase + (size_t)(nt+1)*16*DD;
      #pragma unroll
      for (int ks = 0; ks < 8; ++ks) NB[ks] = *(const half8_t*)(np_ + ks*32);
    }
    f32x4 acc[4];
    #pragma unroll
    for (int mt = 0; mt < 4; ++mt) acc[mt] = (f32x4){0.f,0.f,0.f,0.f};
    #pragma unroll
    for (int ks = 0; ks < 8; ++ks) {
      #pragma unroll
      for (int mt = 0; mt < 4; ++mt)
        acc[mt] = __builtin_amdgcn_mfma_f32_16x16x32_f16(A[mt][ks], B[ks], acc[mt], 0, 0, 0);
    }
    // scores + running per-lane argmin. C/D: col(code)=lane&15, row=(lane>>4)*4+reg
    int code = wave*256 + nt*16 + ln15;
    float e2v = e2b[code];
    #pragma unroll
    for (int mt = 0; mt < 4; ++mt)
      #pragma unroll
      for (int j = 0; j < 4; ++j) {
        float v = fmaf(-2.f, acc[mt][j], e2v);
        merge3(bv[mt][j], bi[mt][j], sv[mt][j], v, code, FLT_MAX);
      }
    if (nt < 15) {
      #pragma unroll
      for (int ks = 0; ks < 8; ++ks) B[ks] = NB[ks];
    }
  }

  // in-wave reduce across the 16 code-columns (ln15 bits), then cross-wave via LDS
  __shared__ float Lv[8][64], Ls[8][64];
  __shared__ int   Li[8][64];
  #pragma unroll
  for (int mt = 0; mt < 4; ++mt)
    #pragma unroll
    for (int j = 0; j < 4; ++j) {
      float v = bv[mt][j], s = sv[mt][j]; int ix = bi[mt][j];
      #pragma unroll
      for (int m = 1; m <= 8; m <<= 1) {
        float ov = __shfl_xor(v, m);
        int   oi = __shfl_xor(ix, m);
        float os = __shfl_xor(s, m);
        merge3(v, ix, s, ov, oi, os);
      }
      if (ln15 == 0) {
        int rl = mt*16 + lq*4 + j;
        Lv[wave][rl] = v; Li[wave][rl] = ix; Ls[wave][rl] = s;
      }
    }
  __syncthreads();
  if (tid < 64) {
    float v = Lv[0][tid], s = Ls[0][tid]; int ix = Li[0][tid];
    #pragma unroll
    for (int w = 1; w < 8; ++w)
      merge3(v, ix, s, Lv[w][tid], Li[w][tid], Ls[w][tid]);
    int row = row0 + tid;
    codes[row] = ix;
    if (s - v < EPS_REFINE) {
      int pos = atomicAdd(rcount, 1);
      if (pos < REFINE_CAP) rlist[pos] = row;
    }
  }
}

// ---------------- fp64 refinement of near-tie rows ----------------
__global__ __launch_bounds__(256) void refine_kernel(const float* __restrict__ Z,
    const float* __restrict__ Eb, int* __restrict__ codes,
    const int* __restrict__ rlist, const int* __restrict__ rcount)
{
  int cnt = *rcount; if (cnt > REFINE_CAP) cnt = REFINE_CAP;
  __shared__ float zrow[DD];
  __shared__ double wbv[4]; __shared__ int wbi[4];
  for (int li = blockIdx.x; li < cnt; li += gridDim.x) {
    int row = rlist[li];
    __syncthreads();
    if (threadIdx.x < 64) {
      float4 v = *(const float4*)&Z[(size_t)row*DD + threadIdx.x*4];
      *(float4*)&zrow[threadIdx.x*4] = v;
    }
    __syncthreads();
    double bestv = DBL_MAX; int besti = 0x7fffffff;
    for (int k = threadIdx.x; k < KK; k += 256) {
      const float* er = Eb + (size_t)k*DD;
      double s = 0.0;
      for (int d = 0; d < DD; d += 4) {
        float4 e = *(const float4*)(er + d);
        double d0 = (double)zrow[d+0] - (double)e.x; s += d0*d0;
        double d1 = (double)zrow[d+1] - (double)e.y; s += d1*d1;
        double d2 = (double)zrow[d+2] - (double)e.z; s += d2*d2;
        double d3 = (double)zrow[d+3] - (double)e.w; s += d3*d3;
      }
      if (s < bestv || (s == bestv && k < besti)) { bestv = s; besti = k; }
    }
    #pragma unroll
    for (int m = 1; m <= 32; m <<= 1) {
      double ov = __shfl_xor(bestv, m);
      int    oi = __shfl_xor(besti, m);
      if (ov < bestv || (ov == bestv && oi < besti)) { bestv = ov; besti = oi; }
    }
    int wv = threadIdx.x >> 6, ln = threadIdx.x & 63;
    if (ln == 0) { wbv[wv] = bestv; wbi[wv] = besti; }
    __syncthreads();
    if (threadIdx.x == 0) {
      double bvv = wbv[0]; int bii = wbi[0];
      for (int w = 1; w < 4; ++w)
        if (wbv[w] < bvv || (wbv[w] == bvv && wbi[w] < bii)) { bvv = wbv[w]; bii = wbi[w]; }
      codes[row] = bii;
    }
    __syncthreads();
  }
}

// ---------------- residual subtract + acoustic accumulate + emit code as float ----------------
__global__ __launch_bounds__(256) void subtract_kernel(float* __restrict__ xa,
    float* __restrict__ aco, const float* __restrict__ Eb,
    const int* __restrict__ codes, float* __restrict__ codes_f,
    int* __restrict__ rcount, int book, int do_sub)
{
  if (blockIdx.x == 0 && threadIdx.x == 0) *rcount = 0;
  int gid = blockIdx.x*256 + threadIdx.x;
  int row = gid >> 6, lane = gid & 63;
  if (row >= MM) return;
  int code = codes[row];
  if (lane == 0) {
    int b = row >> 12, t = row & (TT-1);
    codes_f[((size_t)b*NBOOKS + book)*TT + t] = (float)code;
  }
  if (do_sub) {
    size_t zi = (size_t)row*DD + lane*4;
    float4 e = *(const float4*)&Eb[(size_t)code*DD + lane*4];
    float4 v = *(const float4*)&xa[zi];
    v.x -= e.x; v.y -= e.y; v.z -= e.z; v.w -= e.w;
    *(float4*)&xa[zi] = v;
    float4 a = *(const float4*)&aco[zi];
    a.x += e.x; a.y += e.y; a.z += e.z; a.w += e.w;
    *(float4*)&aco[zi] = a;
  }
}

// ---------------- decode ----------------
__global__ __launch_bounds__(256) void final_kernel(
    const float* __restrict__ Wos, const float* __restrict__ Woa,
    const float* __restrict__ E0, const int* __restrict__ codes0,
    const float* __restrict__ aco, float* __restrict__ out)
{
  __shared__ float wsl[16*68], wal[16*68], sml[16*68], acl[16*68];
  const int tid = threadIdx.x;
  const int t0 = blockIdx.x*64, c0 = blockIdx.y*64, b = blockIdx.z;
  const int u = tid & 63, dq = tid >> 6;
  const int tx = tid & 15, ty = tid >> 4;
  int code = codes0[b*TT + t0 + u];
  const float* smr = E0 + (size_t)code*DD;
  const float* acr = aco + (size_t)(b*TT + t0 + u)*DD;
  const float* wsr = Wos + (size_t)(c0+u)*DD;
  const float* war = Woa + (size_t)(c0+u)*DD;
  float accS[4][4] = {{0}}, accA[4][4] = {{0}};
  for (int dc0 = 0; dc0 < DD; dc0 += 16) {
    __syncthreads();
    float4 v;
    v = *(const float4*)(wsr + dc0 + dq*4);
    wsl[(dq*4+0)*68+u]=v.x; wsl[(dq*4+1)*68+u]=v.y; wsl[(dq*4+2)*68+u]=v.z; wsl[(dq*4+3)*68+u]=v.w;
    v = *(const float4*)(war + dc0 + dq*4);
    wal[(dq*4+0)*68+u]=v.x; wal[(dq*4+1)*68+u]=v.y; wal[(dq*4+2)*68+u]=v.z; wal[(dq*4+3)*68+u]=v.w;
    v = *(const float4*)(smr + dc0 + dq*4);
    sml[(dq*4+0)*68+u]=v.x; sml[(dq*4+1)*68+u]=v.y; sml[(dq*4+2)*68+u]=v.z; sml[(dq*4+3)*68+u]=v.w;
    v = *(const float4*)(acr + dc0 + dq*4);
    acl[(dq*4+0)*68+u]=v.x; acl[(dq*4+1)*68+u]=v.y; acl[(dq*4+2)*68+u]=v.z; acl[(dq*4+3)*68+u]=v.w;
    __syncthreads();
    #pragma unroll
    for (int d = 0; d < 16; ++d) {
      float4 cs = *(const float4*)&wsl[d*68 + tx*4];
      float4 ca = *(const float4*)&wal[d*68 + tx*4];
      float4 ts = *(const float4*)&sml[d*68 + ty*4];
      float4 ta = *(const float4*)&acl[d*68 + ty*4];
      float csf[4]={cs.x,cs.y,cs.z,cs.w}, caf[4]={ca.x,ca.y,ca.z,ca.w};
      float tsf[4]={ts.x,ts.y,ts.z,ts.w}, taf[4]={ta.x,ta.y,ta.z,ta.w};
      #pragma unroll
      for (int i = 0; i < 4; ++i)
        #pragma unroll
        for (int j = 0; j < 4; ++j) {
          accS[i][j] = fmaf(csf[i], tsf[j], accS[i][j]);
          accA[i][j] = fmaf(caf[i], taf[j], accA[i][j]);
        }
    }
  }
  size_t ob = (size_t)b*CC*TT;
  #pragma unroll
  for (int i = 0; i < 4; ++i) {
    float4 r;
    r.x = accS[i][0] + accA[i][0];
    r.y = accS[i][1] + accA[i][1];
    r.z = accS[i][2] + accA[i][2];
    r.w = accS[i][3] + accA[i][3];
    *(float4*)&out[ob + (size_t)(c0 + tx*4 + i)*TT + t0 + ty*4] = r;
  }
}

extern "C" void kernel_launch(void* const* d_in, const int* in_sizes, int n_in,
                              void* d_out, int out_size, void* d_ws, size_t ws_size,
                              hipStream_t stream) {
  const float* x    = (const float*)d_in[0];
  const float* Wins = (const float*)d_in[1];
  const float* Wina = (const float*)d_in[2];
  const float* Wos  = (const float*)d_in[3];
  const float* Woa  = (const float*)d_in[4];
  const float* E    = (const float*)d_in[5];
  float* out = (float*)d_out;
  float* codes_f = out + (size_t)BB*CC*TT;

  // E16 plane lives in the front of d_out (18.9MB; codes_f starts at 33.6MB;
  // out[0:8.4M floats] fully overwritten by final_kernel afterwards).
  _Float16* E16 = (_Float16*)d_out;

  float* xs  = (float*)d_ws;
  float* xa  = xs + (size_t)MM*DD;
  float* aco = xa + (size_t)MM*DD;
  float* e2  = aco + (size_t)MM*DD;
  int* codes_i = (int*)(e2 + 18*KK);
  int* rlist = codes_i + (size_t)NBOOKS*MM;
  int* rcount = rlist + REFINE_CAP;

  static const int BOOKS[21] = {1,2,3,4,5,6,7,8,9,10,11,12,13,14,15,16,17,17,17,17,17};

  hipMemsetAsync(aco, 0, (size_t)MM*DD*sizeof(float), stream);
  proj_kernel<<<dim3(TT/64, DD/64, BB), 256, 0, stream>>>(x, Wins, Wina, xs, xa);
  e2_kernel<<<(18*KK*64)/256, 256, 0, stream>>>(E, e2, rcount);
  cvt_e16_kernel<<<(18*KK*DD)/8/256, 256, 0, stream>>>(E, E16);

  // semantic book (E[0], no residual subtract)
  search_kernel<<<MM/64, 512, 0, stream>>>(xs, E16, e2, codes_i, rcount, rlist);
  refine_kernel<<<256, 256, 0, stream>>>(xs, E, codes_i, rlist, rcount);
  subtract_kernel<<<(MM*64)/256, 256, 0, stream>>>(xa, aco, E, codes_i, codes_f, rcount, 0, 0);

  for (int ib = 0; ib < 21; ++ib) {
    int cb = BOOKS[ib];
    const float* Eb  = E  + (size_t)cb*KK*DD;
    const _Float16* E16b = E16 + (size_t)cb*KK*DD;
    const float* e2b = e2 + (size_t)cb*KK;
    int* cbk = codes_i + (size_t)(ib+1)*MM;
    search_kernel<<<MM/64, 512, 0, stream>>>(xa, E16b, e2b, cbk, rcount, rlist);
    refine_kernel<<<256, 256, 0, stream>>>(xa, Eb, cbk, rlist, rcount);
    subtract_kernel<<<(MM*64)/256, 256, 0, stream>>>(xa, aco, Eb, cbk, codes_f, rcount, ib+1, 1);
  }

  final_kernel<<<dim3(TT/64, CC/64, BB), 256, 0, stream>>>(Wos, Woa, E, codes_i, aco, out);
}

// Round 6
// 3710.247 us; speedup vs baseline: 11.1394x; 1.0172x over previous
//
#include <hip/hip_runtime.h>
#include <float.h>

#define TT 4096
#define BB 4
#define CC 512
#define DD 256
#define KK 2048
#define MM (BB*TT)        // 16384 rows (b,t)
#define NBOOKS 22
#define REFINE_CAP 16384
#define EPS_REFINE 0.25f

typedef _Float16 half8_t __attribute__((ext_vector_type(8)));
typedef float f32x4 __attribute__((ext_vector_type(4)));

// merge (best value, best idx, second-best value) triples; ties -> lower idx (np.argmin semantics)
__device__ __forceinline__ void merge3(float& bv, int& bi, float& sv,
                                       float ov, int oi, float osv) {
  if (ov < bv || (ov == bv && oi < bi)) {
    sv = fminf(bv, osv);
    bv = ov; bi = oi;
  } else {
    sv = fminf(sv, ov);
  }
}

// ---------------- projection: xs = Win_s @ x, xa = Win_a @ x  (per b: [256x512]@[512x4096]) ----------------
__global__ __launch_bounds__(256) void proj_kernel(const float* __restrict__ x,
    const float* __restrict__ Ws, const float* __restrict__ Wa,
    float* __restrict__ xs, float* __restrict__ xa)
{
  __shared__ float xt[16*64];     // [c][t]
  __shared__ float wsl[16*68];    // [c][d] padded
  __shared__ float wal[16*68];
  const int tid = threadIdx.x;
  const int t0 = blockIdx.x*64, d0 = blockIdx.y*64, b = blockIdx.z;
  const int u = tid & 63, cq = tid >> 6;
  const int tx = tid & 15, ty = tid >> 4;
  const float* xb = x + (size_t)b*CC*TT;
  float accS[4][4] = {{0}}, accA[4][4] = {{0}};
  for (int c0 = 0; c0 < CC; c0 += 16) {
    __syncthreads();
    #pragma unroll
    for (int i = 0; i < 4; ++i) {
      int cc = cq*4 + i;
      xt[cc*64 + u] = xb[(size_t)(c0+cc)*TT + t0 + u];
    }
    {
      float4 wv = *(const float4*)&Ws[(size_t)(d0+u)*CC + c0 + cq*4];
      wsl[(cq*4+0)*68 + u] = wv.x; wsl[(cq*4+1)*68 + u] = wv.y;
      wsl[(cq*4+2)*68 + u] = wv.z; wsl[(cq*4+3)*68 + u] = wv.w;
      wv = *(const float4*)&Wa[(size_t)(d0+u)*CC + c0 + cq*4];
      wal[(cq*4+0)*68 + u] = wv.x; wal[(cq*4+1)*68 + u] = wv.y;
      wal[(cq*4+2)*68 + u] = wv.z; wal[(cq*4+3)*68 + u] = wv.w;
    }
    __syncthreads();
    #pragma unroll
    for (int cc = 0; cc < 16; ++cc) {
      float4 tq = *(const float4*)&xt[cc*64 + ty*4];
      float4 sq = *(const float4*)&wsl[cc*68 + tx*4];
      float4 aq = *(const float4*)&wal[cc*68 + tx*4];
      float tf[4] = {tq.x,tq.y,tq.z,tq.w};
      float sf[4] = {sq.x,sq.y,sq.z,sq.w};
      float af[4] = {aq.x,aq.y,aq.z,aq.w};
      #pragma unroll
      for (int i = 0; i < 4; ++i)
        #pragma unroll
        for (int j = 0; j < 4; ++j) {
          accS[i][j] = fmaf(tf[i], sf[j], accS[i][j]);
          accA[i][j] = fmaf(tf[i], af[j], accA[i][j]);
        }
    }
  }
  #pragma unroll
  for (int i = 0; i < 4; ++i) {
    size_t r = (size_t)b*TT + t0 + ty*4 + i;
    float4 o;
    o.x = accS[i][0]; o.y = accS[i][1]; o.z = accS[i][2]; o.w = accS[i][3];
    *(float4*)&xs[r*DD + d0 + tx*4] = o;
    o.x = accA[i][0]; o.y = accA[i][1]; o.z = accA[i][2]; o.w = accA[i][3];
    *(float4*)&xa[r*DD + d0 + tx*4] = o;
  }
}

// ---------------- e2[k] = sum_d E[k][d]^2 ----------------
__global__ __launch_bounds__(256) void e2_kernel(const float* __restrict__ E,
    float* __restrict__ e2, int* __restrict__ rcount)
{
  int gid = blockIdx.x*256 + threadIdx.x;
  int wid = gid >> 6, lane = gid & 63;
  if (wid < 18*KK) {
    float4 v = *(const float4*)&E[(size_t)wid*DD + lane*4];
    float s = v.x*v.x + v.y*v.y + v.z*v.z + v.w*v.w;
    #pragma unroll
    for (int m = 1; m <= 32; m <<= 1) s += __shfl_xor(s, m);
    if (lane == 0) e2[wid] = s;
  }
  if (blockIdx.x == 0 && threadIdx.x == 0) *rcount = 0;
}

// ---------------- convert E -> f16 plane (stored in front of d_out, dead by final_kernel) ----------------
__global__ __launch_bounds__(256) void cvt_e16_kernel(const float* __restrict__ E,
    _Float16* __restrict__ E16)
{
  size_t i = ((size_t)blockIdx.x*256 + threadIdx.x)*8;
  float4 u = *(const float4*)&E[i];
  float4 v = *(const float4*)&E[i+4];
  half8_t h;
  h[0]=(_Float16)u.x; h[1]=(_Float16)u.y; h[2]=(_Float16)u.z; h[3]=(_Float16)u.w;
  h[4]=(_Float16)v.x; h[5]=(_Float16)v.y; h[6]=(_Float16)v.z; h[7]=(_Float16)v.w;
  *(half8_t*)&E16[i] = h;
}

// ---------------- nearest-code search via f16 MFMA ----------------
// 256 blocks x 64 rows. 512 threads = 8 waves; ALL waves hold the same 64 rows
// of A (4 M-tiles, f32->f16, in registers); wave w owns codes [w*256, w*256+256).
// Register budget ~250 (<=256 via launch_bounds(512,2)) => 2 waves/SIMD.
// Pipeline: NB[0..3] = next-nt k0..3 issued at nt start (~1 nt of cover);
// B[4..7] = next-nt k4..7 reissued at nt end.
__global__ __launch_bounds__(512, 2) void search_kernel(
    const float* __restrict__ Z, const _Float16* __restrict__ E16b,
    const float* __restrict__ e2b, int* __restrict__ codes,
    int* __restrict__ rcount, int* __restrict__ rlist)
{
  const int tid = threadIdx.x;
  const int lane = tid & 63, wave = tid >> 6;
  const int ln15 = lane & 15, lq = lane >> 4;  // lq 0..3
  const int row0 = blockIdx.x * 64;

  // A fragments: 4 M-tiles x 8 k-steps (whole 64-row, 256-k panel), held all book
  half8_t A[4][8];
  #pragma unroll
  for (int mt = 0; mt < 4; ++mt) {
    const float* zr = Z + (size_t)(row0 + mt*16 + ln15)*DD + lq*8;
    #pragma unroll
    for (int ks = 0; ks < 8; ++ks) {
      float4 u = *(const float4*)(zr + ks*32);
      float4 v = *(const float4*)(zr + ks*32 + 4);
      half8_t a;
      a[0]=(_Float16)u.x; a[1]=(_Float16)u.y; a[2]=(_Float16)u.z; a[3]=(_Float16)u.w;
      a[4]=(_Float16)v.x; a[5]=(_Float16)v.y; a[6]=(_Float16)v.z; a[7]=(_Float16)v.w;
      A[mt][ks] = a;
    }
  }

  float bv[4][4], sv[4][4]; int bi[4][4];
  #pragma unroll
  for (int mt = 0; mt < 4; ++mt)
    #pragma unroll
    for (int j = 0; j < 4; ++j) { bv[mt][j] = FLT_MAX; sv[mt][j] = FLT_MAX; bi[mt][j] = 0x7fffffff; }

  const _Float16* ebase = E16b + (size_t)(wave*256 + ln15)*DD + lq*8;

  half8_t B[8], NB[4];
  #pragma unroll
  for (int ks = 0; ks < 8; ++ks) B[ks] = *(const half8_t*)(ebase + ks*32);

  for (int nt = 0; nt < 16; ++nt) {
    const _Float16* nx = ebase + (size_t)(nt+1)*16*DD;
    if (nt < 15) {                       // prefetch next-nt k0..3 (used ~1 nt later)
      NB[0] = *(const half8_t*)(nx + 0*32);
      NB[1] = *(const half8_t*)(nx + 1*32);
      NB[2] = *(const half8_t*)(nx + 2*32);
      NB[3] = *(const half8_t*)(nx + 3*32);
    }
    float e2v = e2b[wave*256 + nt*16 + ln15];
    f32x4 acc[4];
    #pragma unroll
    for (int mt = 0; mt < 4; ++mt) acc[mt] = (f32x4){0.f,0.f,0.f,0.f};
    #pragma unroll
    for (int ks = 0; ks < 8; ++ks) {
      #pragma unroll
      for (int mt = 0; mt < 4; ++mt)
        acc[mt] = __builtin_amdgcn_mfma_f32_16x16x32_f16(A[mt][ks], B[ks], acc[mt], 0, 0, 0);
    }
    // scores + running per-lane argmin. C/D: col(code)=lane&15, row=(lane>>4)*4+reg
    int code = wave*256 + nt*16 + ln15;
    #pragma unroll
    for (int mt = 0; mt < 4; ++mt)
      #pragma unroll
      for (int j = 0; j < 4; ++j) {
        float v = fmaf(-2.f, acc[mt][j], e2v);
        merge3(bv[mt][j], bi[mt][j], sv[mt][j], v, code, FLT_MAX);
      }
    if (nt < 15) {                       // rotate + reissue k4..7 of next nt
      B[0] = NB[0]; B[1] = NB[1]; B[2] = NB[2]; B[3] = NB[3];
      B[4] = *(const half8_t*)(nx + 4*32);
      B[5] = *(const half8_t*)(nx + 5*32);
      B[6] = *(const half8_t*)(nx + 6*32);
      B[7] = *(const half8_t*)(nx + 7*32);
    }
  }

  // in-wave reduce across the 16 code-columns (ln15 bits), then cross-wave via LDS
  __shared__ float Lv[8][64], Ls[8][64];
  __shared__ int   Li[8][64];
  #pragma unroll
  for (int mt = 0; mt < 4; ++mt)
    #pragma unroll
    for (int j = 0; j < 4; ++j) {
      float v = bv[mt][j], s = sv[mt][j]; int ix = bi[mt][j];
      #pragma unroll
      for (int m = 1; m <= 8; m <<= 1) {
        float ov = __shfl_xor(v, m);
        int   oi = __shfl_xor(ix, m);
        float os = __shfl_xor(s, m);
        merge3(v, ix, s, ov, oi, os);
      }
      if (ln15 == 0) {
        int rl = mt*16 + lq*4 + j;
        Lv[wave][rl] = v; Li[wave][rl] = ix; Ls[wave][rl] = s;
      }
    }
  __syncthreads();
  if (tid < 64) {
    float v = Lv[0][tid], s = Ls[0][tid]; int ix = Li[0][tid];
    #pragma unroll
    for (int w = 1; w < 8; ++w)
      merge3(v, ix, s, Lv[w][tid], Li[w][tid], Ls[w][tid]);
    int row = row0 + tid;
    codes[row] = ix;
    if (s - v < EPS_REFINE) {
      int pos = atomicAdd(rcount, 1);
      if (pos < REFINE_CAP) rlist[pos] = row;
    }
  }
}

// ---------------- fp64 refinement of near-tie rows ----------------
__global__ __launch_bounds__(256) void refine_kernel(const float* __restrict__ Z,
    const float* __restrict__ Eb, int* __restrict__ codes,
    const int* __restrict__ rlist, const int* __restrict__ rcount)
{
  int cnt = *rcount; if (cnt > REFINE_CAP) cnt = REFINE_CAP;
  __shared__ float zrow[DD];
  __shared__ double wbv[4]; __shared__ int wbi[4];
  for (int li = blockIdx.x; li < cnt; li += gridDim.x) {
    int row = rlist[li];
    __syncthreads();
    if (threadIdx.x < 64) {
      float4 v = *(const float4*)&Z[(size_t)row*DD + threadIdx.x*4];
      *(float4*)&zrow[threadIdx.x*4] = v;
    }
    __syncthreads();
    double bestv = DBL_MAX; int besti = 0x7fffffff;
    for (int k = threadIdx.x; k < KK; k += 256) {
      const float* er = Eb + (size_t)k*DD;
      double s = 0.0;
      for (int d = 0; d < DD; d += 4) {
        float4 e = *(const float4*)(er + d);
        double d0 = (double)zrow[d+0] - (double)e.x; s += d0*d0;
        double d1 = (double)zrow[d+1] - (double)e.y; s += d1*d1;
        double d2 = (double)zrow[d+2] - (double)e.z; s += d2*d2;
        double d3 = (double)zrow[d+3] - (double)e.w; s += d3*d3;
      }
      if (s < bestv || (s == bestv && k < besti)) { bestv = s; besti = k; }
    }
    #pragma unroll
    for (int m = 1; m <= 32; m <<= 1) {
      double ov = __shfl_xor(bestv, m);
      int    oi = __shfl_xor(besti, m);
      if (ov < bestv || (ov == bestv && oi < besti)) { bestv = ov; besti = oi; }
    }
    int wv = threadIdx.x >> 6, ln = threadIdx.x & 63;
    if (ln == 0) { wbv[wv] = bestv; wbi[wv] = besti; }
    __syncthreads();
    if (threadIdx.x == 0) {
      double bvv = wbv[0]; int bii = wbi[0];
      for (int w = 1; w < 4; ++w)
        if (wbv[w] < bvv || (wbv[w] == bvv && wbi[w] < bii)) { bvv = wbv[w]; bii = wbi[w]; }
      codes[row] = bii;
    }
    __syncthreads();
  }
}

// ---------------- residual subtract + acoustic accumulate + emit code as float ----------------
__global__ __launch_bounds__(256) void subtract_kernel(float* __restrict__ xa,
    float* __restrict__ aco, const float* __restrict__ Eb,
    const int* __restrict__ codes, float* __restrict__ codes_f,
    int* __restrict__ rcount, int book, int do_sub)
{
  if (blockIdx.x == 0 && threadIdx.x == 0) *rcount = 0;
  int gid = blockIdx.x*256 + threadIdx.x;
  int row = gid >> 6, lane = gid & 63;
  if (row >= MM) return;
  int code = codes[row];
  if (lane == 0) {
    int b = row >> 12, t = row & (TT-1);
    codes_f[((size_t)b*NBOOKS + book)*TT + t] = (float)code;
  }
  if (do_sub) {
    size_t zi = (size_t)row*DD + lane*4;
    float4 e = *(const float4*)&Eb[(size_t)code*DD + lane*4];
    float4 v = *(const float4*)&xa[zi];
    v.x -= e.x; v.y -= e.y; v.z -= e.z; v.w -= e.w;
    *(float4*)&xa[zi] = v;
    float4 a = *(const float4*)&aco[zi];
    a.x += e.x; a.y += e.y; a.z += e.z; a.w += e.w;
    *(float4*)&aco[zi] = a;
  }
}

// ---------------- decode ----------------
__global__ __launch_bounds__(256) void final_kernel(
    const float* __restrict__ Wos, const float* __restrict__ Woa,
    const float* __restrict__ E0, const int* __restrict__ codes0,
    const float* __restrict__ aco, float* __restrict__ out)
{
  __shared__ float wsl[16*68], wal[16*68], sml[16*68], acl[16*68];
  const int tid = threadIdx.x;
  const int t0 = blockIdx.x*64, c0 = blockIdx.y*64, b = blockIdx.z;
  const int u = tid & 63, dq = tid >> 6;
  const int tx = tid & 15, ty = tid >> 4;
  int code = codes0[b*TT + t0 + u];
  const float* smr = E0 + (size_t)code*DD;
  const float* acr = aco + (size_t)(b*TT + t0 + u)*DD;
  const float* wsr = Wos + (size_t)(c0+u)*DD;
  const float* war = Woa + (size_t)(c0+u)*DD;
  float accS[4][4] = {{0}}, accA[4][4] = {{0}};
  for (int dc0 = 0; dc0 < DD; dc0 += 16) {
    __syncthreads();
    float4 v;
    v = *(const float4*)(wsr + dc0 + dq*4);
    wsl[(dq*4+0)*68+u]=v.x; wsl[(dq*4+1)*68+u]=v.y; wsl[(dq*4+2)*68+u]=v.z; wsl[(dq*4+3)*68+u]=v.w;
    v = *(const float4*)(war + dc0 + dq*4);
    wal[(dq*4+0)*68+u]=v.x; wal[(dq*4+1)*68+u]=v.y; wal[(dq*4+2)*68+u]=v.z; wal[(dq*4+3)*68+u]=v.w;
    v = *(const float4*)(smr + dc0 + dq*4);
    sml[(dq*4+0)*68+u]=v.x; sml[(dq*4+1)*68+u]=v.y; sml[(dq*4+2)*68+u]=v.z; sml[(dq*4+3)*68+u]=v.w;
    v = *(const float4*)(acr + dc0 + dq*4);
    acl[(dq*4+0)*68+u]=v.x; acl[(dq*4+1)*68+u]=v.y; acl[(dq*4+2)*68+u]=v.z; acl[(dq*4+3)*68+u]=v.w;
    __syncthreads();
    #pragma unroll
    for (int d = 0; d < 16; ++d) {
      float4 cs = *(const float4*)&wsl[d*68 + tx*4];
      float4 ca = *(const float4*)&wal[d*68 + tx*4];
      float4 ts = *(const float4*)&sml[d*68 + ty*4];
      float4 ta = *(const float4*)&acl[d*68 + ty*4];
      float csf[4]={cs.x,cs.y,cs.z,cs.w}, caf[4]={ca.x,ca.y,ca.z,ca.w};
      float tsf[4]={ts.x,ts.y,ts.z,ts.w}, taf[4]={ta.x,ta.y,ta.z,ta.w};
      #pragma unroll
      for (int i = 0; i < 4; ++i)
        #pragma unroll
        for (int j = 0; j < 4; ++j) {
          accS[i][j] = fmaf(csf[i], tsf[j], accS[i][j]);
          accA[i][j] = fmaf(caf[i], taf[j], accA[i][j]);
        }
    }
  }
  size_t ob = (size_t)b*CC*TT;
  #pragma unroll
  for (int i = 0; i < 4; ++i) {
    float4 r;
    r.x = accS[i][0] + accA[i][0];
    r.y = accS[i][1] + accA[i][1];
    r.z = accS[i][2] + accA[i][2];
    r.w = accS[i][3] + accA[i][3];
    *(float4*)&out[ob + (size_t)(c0 + tx*4 + i)*TT + t0 + ty*4] = r;
  }
}

extern "C" void kernel_launch(void* const* d_in, const int* in_sizes, int n_in,
                              void* d_out, int out_size, void* d_ws, size_t ws_size,
                              hipStream_t stream) {
  const float* x    = (const float*)d_in[0];
  const float* Wins = (const float*)d_in[1];
  const float* Wina = (const float*)d_in[2];
  const float* Wos  = (const float*)d_in[3];
  const float* Woa  = (const float*)d_in[4];
  const float* E    = (const float*)d_in[5];
  float* out = (float*)d_out;
  float* codes_f = out + (size_t)BB*CC*TT;

  // E16 plane lives in the front of d_out (18.9MB; codes_f starts at 33.6MB;
  // out[0:8.4M floats] fully overwritten by final_kernel afterwards).
  _Float16* E16 = (_Float16*)d_out;

  float* xs  = (float*)d_ws;
  float* xa  = xs + (size_t)MM*DD;
  float* aco = xa + (size_t)MM*DD;
  float* e2  = aco + (size_t)MM*DD;
  int* codes_i = (int*)(e2 + 18*KK);
  int* rlist = codes_i + (size_t)NBOOKS*MM;
  int* rcount = rlist + REFINE_CAP;

  static const int BOOKS[21] = {1,2,3,4,5,6,7,8,9,10,11,12,13,14,15,16,17,17,17,17,17};

  hipMemsetAsync(aco, 0, (size_t)MM*DD*sizeof(float), stream);
  proj_kernel<<<dim3(TT/64, DD/64, BB), 256, 0, stream>>>(x, Wins, Wina, xs, xa);
  e2_kernel<<<(18*KK*64)/256, 256, 0, stream>>>(E, e2, rcount);
  cvt_e16_kernel<<<(18*KK*DD)/8/256, 256, 0, stream>>>(E, E16);

  // semantic book (E[0], no residual subtract)
  search_kernel<<<MM/64, 512, 0, stream>>>(xs, E16, e2, codes_i, rcount, rlist);
  refine_kernel<<<2048, 256, 0, stream>>>(xs, E, codes_i, rlist, rcount);
  subtract_kernel<<<(MM*64)/256, 256, 0, stream>>>(xa, aco, E, codes_i, codes_f, rcount, 0, 0);

  for (int ib = 0; ib < 21; ++ib) {
    int cb = BOOKS[ib];
    const float* Eb  = E  + (size_t)cb*KK*DD;
    const _Float16* E16b = E16 + (size_t)cb*KK*DD;
    const float* e2b = e2 + (size_t)cb*KK;
    int* cbk = codes_i + (size_t)(ib+1)*MM;
    search_kernel<<<MM/64, 512, 0, stream>>>(xa, E16b, e2b, cbk, rcount, rlist);
    refine_kernel<<<2048, 256, 0, stream>>>(xa, Eb, cbk, rlist, rcount);
    subtract_kernel<<<(MM*64)/256, 256, 0, stream>>>(xa, aco, Eb, cbk, codes_f, rcount, ib+1, 1);
  }

  final_kernel<<<dim3(TT/64, CC/64, BB), 256, 0, stream>>>(Wos, Woa, E, codes_i, aco, out);
}